// Round 1
// baseline (252.995 us; speedup 1.0000x reference)
//
#include <hip/hip_runtime.h>
#include <stdint.h>

#define DIM 768
#define NP  784
#define NH  12
#define HD  64
#define BATCH 8
#define MROWS (BATCH*NP)   // 6272

using bf16x8 = __attribute__((ext_vector_type(8))) short;
using bf16x4 = __attribute__((ext_vector_type(4))) short;
using f32x4  = __attribute__((ext_vector_type(4))) float;

__device__ __forceinline__ short f2bf(float f) {
  union { float f; uint32_t u; } c; c.f = f;
  uint32_t u = c.u;
  u += 0x7FFFu + ((u >> 16) & 1u);   // RNE
  return (short)(u >> 16);
}

__device__ __forceinline__ void gld_lds16(const void* g, void* l) {
  __builtin_amdgcn_global_load_lds((const __attribute__((address_space(1))) uint32_t*)g,
                                   (__attribute__((address_space(3))) uint32_t*)l,
                                   16, 0, 0);
}

// ---------------- prep: x_s -> bf16 ----------------
__global__ __launch_bounds__(256) void cvt_bf16_kernel(const float* __restrict__ src,
                                                       short* __restrict__ dst, int n8) {
  int i = blockIdx.x * 256 + threadIdx.x;
  if (i >= n8) return;
  const float4* s = (const float4*)src;
  float4 a = s[2*i], b = s[2*i+1];
  bf16x8 o;
  o[0]=f2bf(a.x); o[1]=f2bf(a.y); o[2]=f2bf(a.z); o[3]=f2bf(a.w);
  o[4]=f2bf(b.x); o[5]=f2bf(b.y); o[6]=f2bf(b.z); o[7]=f2bf(b.w);
  ((bf16x8*)dst)[i] = o;
}

// ---------------- prep: W[k][n] -> Wt[n][k] bf16 (4 matrices) ----------------
__global__ __launch_bounds__(256) void wtrans_kernel(const float* __restrict__ w0,
                                                     const float* __restrict__ w1,
                                                     const float* __restrict__ w2,
                                                     const float* __restrict__ w3,
                                                     short* __restrict__ dst) {
  __shared__ float tile[32][33];
  const int z = blockIdx.z;
  const float* src = (z==0) ? w0 : (z==1) ? w1 : (z==2) ? w2 : w3;
  short* d = dst + (size_t)z * DIM * DIM;
  const int n0 = blockIdx.x*32, k0 = blockIdx.y*32;
  const int tx = threadIdx.x, ty = threadIdx.y;  // (32,8)
#pragma unroll
  for (int i=0;i<4;i++) tile[ty+i*8][tx] = src[(size_t)(k0+ty+i*8)*DIM + n0+tx];
  __syncthreads();
#pragma unroll
  for (int i=0;i<4;i++) d[(size_t)(n0+ty+i*8)*DIM + k0+tx] = f2bf(tile[tx][ty+i*8]);
}

// ---------------- prep: t[z][b][d] = x_t[b] @ Wt_z ----------------
__global__ __launch_bounds__(256) void tvec_kernel(const float* __restrict__ x_t,
                                                   const float* __restrict__ wq,
                                                   const float* __restrict__ wk,
                                                   const float* __restrict__ wv,
                                                   float* __restrict__ t) {
  const int z = blockIdx.x, b = blockIdx.y, d = threadIdx.x;
  const float* w = (z==0) ? wq : (z==1) ? wk : wv;
  const float* xt = x_t + (size_t)b * DIM;
  float a0=0.f, a1=0.f, a2=0.f;
  for (int k=0;k<DIM;k++) {
    float xv = xt[k];
    const float* wr = w + (size_t)k*DIM + d;
    a0 += xv * wr[0];
    a1 += xv * wr[256];
    a2 += xv * wr[512];
  }
  float* o = t + ((size_t)z*BATCH + b) * DIM;
  o[d]=a0; o[d+256]=a1; o[d+512]=a2;
}

// ---------------- GEMM: C[m][n] = A[m][k] * Bt[n][k]  (bf16 in, f32 acc) ----------------
// MODE 0: QKV — epilogue adds t-vec, scales Q by 0.125, stores bf16 (grid.z = 0,1,2)
// MODE 1: proj — epilogue adds bias, stores f32
template<int MODE>
__global__ __launch_bounds__(256) void gemm_kernel(const short* __restrict__ A,
                                                   const short* __restrict__ Bw,
                                                   const float* __restrict__ aux,
                                                   short* __restrict__ outb,
                                                   float* __restrict__ outf) {
  __shared__ short As[128*32];
  __shared__ short Bs[128*32];
  const int bx = blockIdx.x, by = blockIdx.y, z = blockIdx.z;
  const short* Bz = Bw + (size_t)z * DIM * DIM;
  const int tid = threadIdx.x, w = tid>>6, lane = tid&63;
  const int wr = w>>1, wc = w&1, ln15 = lane&15, lg = lane>>4;
  const int m0 = by*128, n0 = bx*128;

  f32x4 acc[4][4] = {};

  for (int kt=0; kt<24; ++kt) {
    const int k0 = kt*32;
    __syncthreads();
#pragma unroll
    for (int i=0;i<2;i++) {
      const int inst = w*2 + i;
      const int off  = inst*1024 + lane*16;   // byte offset within 8192B tile
      const int row  = off >> 6;              // 64B per row (32 bf16)
      const int ce   = (off & 63) >> 1;       // element within row
      gld_lds16(A  + (size_t)(m0+row)*DIM + k0 + ce, (char*)As + (size_t)inst*1024);
      gld_lds16(Bz + (size_t)(n0+row)*DIM + k0 + ce, (char*)Bs + (size_t)inst*1024);
    }
    __syncthreads();
    bf16x8 af[4], bfr[4];
#pragma unroll
    for (int mi=0;mi<4;mi++) af[mi]  = *(const bf16x8*)&As[(wr*64+mi*16+ln15)*32 + lg*8];
#pragma unroll
    for (int ni=0;ni<4;ni++) bfr[ni] = *(const bf16x8*)&Bs[(wc*64+ni*16+ln15)*32 + lg*8];
#pragma unroll
    for (int mi=0;mi<4;mi++)
#pragma unroll
      for (int ni=0;ni<4;ni++)
        acc[mi][ni] = __builtin_amdgcn_mfma_f32_16x16x32_bf16(af[mi], bfr[ni], acc[mi][ni], 0,0,0);
  }

  if (MODE == 0) {
    short* Oz = outb + (size_t)z * MROWS * DIM;
    const float scl = (z==0) ? 0.125f : 1.0f;
#pragma unroll
    for (int mi=0;mi<4;mi++) {
#pragma unroll
      for (int j=0;j<4;j++) {
        const int r  = m0 + wr*64 + mi*16 + lg*4 + j;   // C row = (lane>>4)*4 + reg
        const int bb = r / NP;
        const float* tv = aux + ((size_t)z*BATCH + bb) * DIM;
#pragma unroll
        for (int ni=0;ni<4;ni++) {
          const int gcol = n0 + wc*64 + ni*16 + ln15;   // C col = lane&15
          Oz[(size_t)r*DIM + gcol] = f2bf((acc[mi][ni][j] + tv[gcol]) * scl);
        }
      }
    }
  } else {
#pragma unroll
    for (int mi=0;mi<4;mi++)
#pragma unroll
      for (int j=0;j<4;j++) {
        const int r = m0 + wr*64 + mi*16 + lg*4 + j;
#pragma unroll
        for (int ni=0;ni<4;ni++) {
          const int gcol = n0 + wc*64 + ni*16 + ln15;
          outf[(size_t)r*DIM + gcol] = acc[mi][ni][j] + aux[gcol];
        }
      }
  }
}

// ---------------- flash attention ----------------
// grid (13, 12, 8); block 256 = 4 waves; wave w owns q-rows [q0+w*16, +16)
// Swapped QK^T: S^T = mfma(K_tile, Q^T) -> lane holds col q = lane&15, rows m.
// P^T lands exactly in the 16x16x16 B-frag layout; V^T staged in LDS for A-frag.
__global__ __launch_bounds__(256) void attn_kernel(const short* __restrict__ Qb,
                                                   const short* __restrict__ Kb,
                                                   const short* __restrict__ Vb,
                                                   const float* __restrict__ rpb,
                                                   short* __restrict__ Ob) {
  __shared__ float bias_lds[110];
  __shared__ short vt[64*16];    // vt[d][m] for current 16-m tile
  const int qt = blockIdx.x, h = blockIdx.y, b = blockIdx.z;
  const int q0 = qt*64;
  const int tid = threadIdx.x, w = tid>>6, lane = tid&63;
  const int ln15 = lane&15, lg = lane>>4;

  // bias depends only on s = (qr+qc) - (mr+mc) + 54 in [0,108]
  if (tid < 109) bias_lds[tid] = rpb[(tid/55)*(55*NH) + (tid%55)*NH + h];

  const bool active = (q0 + w*16) < NP;   // 784 = 49*16, only whole waves go inactive
  const int q_idx = q0 + w*16 + ln15;
  bf16x8 qf0 = {}, qf1 = {};
  if (active) {
    const short* qp = Qb + (size_t)(b*NP + q_idx)*DIM + h*HD + lg*8;
    qf0 = *(const bf16x8*)qp;
    qf1 = *(const bf16x8*)(qp + 32);
  }
  const int qs = q_idx/28 + q_idx%28;
  float m_run = -__builtin_inff(), l_run = 0.f;
  f32x4 o0 = {}, o1 = {}, o2 = {}, o3 = {};

  const int vml = tid>>4, vd0 = (tid&15)*4;
  const short* vbase = Vb + (size_t)b*NP*DIM + h*HD;

  for (int mt=0; mt<49; ++mt) {
    const int m0 = mt*16;
    __syncthreads();                       // prev PV reads of vt done
    {                                      // stage V^T tile (all threads)
      bf16x4 v4 = *(const bf16x4*)(vbase + (size_t)(m0+vml)*DIM + vd0);
      vt[(vd0+0)*16 + vml] = v4[0];
      vt[(vd0+1)*16 + vml] = v4[1];
      vt[(vd0+2)*16 + vml] = v4[2];
      vt[(vd0+3)*16 + vml] = v4[3];
    }
    f32x4 s4 = {};
    if (active) {                          // QK^T from global (no LDS dep)
      const short* kp = Kb + (size_t)(b*NP + m0 + ln15)*DIM + h*HD + lg*8;
      bf16x8 kf0 = *(const bf16x8*)kp;
      bf16x8 kf1 = *(const bf16x8*)(kp + 32);
      s4 = __builtin_amdgcn_mfma_f32_16x16x32_bf16(kf0, qf0, s4, 0,0,0);
      s4 = __builtin_amdgcn_mfma_f32_16x16x32_bf16(kf1, qf1, s4, 0,0,0);
    }
    __syncthreads();                       // vt ready
    if (active) {
      const int mb = m0 + lg*4;
      s4[0] += bias_lds[qs - ((mb+0)/28 + (mb+0)%28) + 54];
      s4[1] += bias_lds[qs - ((mb+1)/28 + (mb+1)%28) + 54];
      s4[2] += bias_lds[qs - ((mb+2)/28 + (mb+2)%28) + 54];
      s4[3] += bias_lds[qs - ((mb+3)/28 + (mb+3)%28) + 54];
      float tm = fmaxf(fmaxf(s4[0],s4[1]), fmaxf(s4[2],s4[3]));
      tm = fmaxf(tm, __shfl_xor(tm, 16));
      tm = fmaxf(tm, __shfl_xor(tm, 32));
      const float m_new = fmaxf(m_run, tm);
      const float f = __expf(m_run - m_new);
      float p0 = __expf(s4[0]-m_new), p1 = __expf(s4[1]-m_new);
      float p2 = __expf(s4[2]-m_new), p3 = __expf(s4[3]-m_new);
      float ts = p0+p1+p2+p3;
      ts += __shfl_xor(ts, 16);
      ts += __shfl_xor(ts, 32);
      l_run = l_run*f + ts;
      m_run = m_new;
      o0 *= f; o1 *= f; o2 *= f; o3 *= f;
      bf16x4 pbv; pbv[0]=f2bf(p0); pbv[1]=f2bf(p1); pbv[2]=f2bf(p2); pbv[3]=f2bf(p3);
      const int vofs = lg*4;
      bf16x4 vf0 = *(const bf16x4*)&vt[(0*16+ln15)*16 + vofs];
      bf16x4 vf1 = *(const bf16x4*)&vt[(1*16+ln15)*16 + vofs];
      bf16x4 vf2 = *(const bf16x4*)&vt[(2*16+ln15)*16 + vofs];
      bf16x4 vf3 = *(const bf16x4*)&vt[(3*16+ln15)*16 + vofs];
      o0 = __builtin_amdgcn_mfma_f32_16x16x16bf16_1k(vf0, pbv, o0, 0,0,0);
      o1 = __builtin_amdgcn_mfma_f32_16x16x16bf16_1k(vf1, pbv, o1, 0,0,0);
      o2 = __builtin_amdgcn_mfma_f32_16x16x16bf16_1k(vf2, pbv, o2, 0,0,0);
      o3 = __builtin_amdgcn_mfma_f32_16x16x16bf16_1k(vf3, pbv, o3, 0,0,0);
    }
  }
  if (active) {
    const float inv = 1.0f / l_run;
    short* op = Ob + (size_t)(b*NP + q_idx)*DIM + h*HD + lg*4;
    bf16x4 ov;
    ov[0]=f2bf(o0[0]*inv); ov[1]=f2bf(o0[1]*inv); ov[2]=f2bf(o0[2]*inv); ov[3]=f2bf(o0[3]*inv);
    *(bf16x4*)(op + 0*16) = ov;
    ov[0]=f2bf(o1[0]*inv); ov[1]=f2bf(o1[1]*inv); ov[2]=f2bf(o1[2]*inv); ov[3]=f2bf(o1[3]*inv);
    *(bf16x4*)(op + 1*16) = ov;
    ov[0]=f2bf(o2[0]*inv); ov[1]=f2bf(o2[1]*inv); ov[2]=f2bf(o2[2]*inv); ov[3]=f2bf(o2[3]*inv);
    *(bf16x4*)(op + 2*16) = ov;
    ov[0]=f2bf(o3[0]*inv); ov[1]=f2bf(o3[1]*inv); ov[2]=f2bf(o3[2]*inv); ov[3]=f2bf(o3[3]*inv);
    *(bf16x4*)(op + 3*16) = ov;
  }
}

extern "C" void kernel_launch(void* const* d_in, const int* in_sizes, int n_in,
                              void* d_out, int out_size, void* d_ws, size_t ws_size,
                              hipStream_t stream) {
  const float* x_s = (const float*)d_in[0];
  const float* x_t = (const float*)d_in[1];
  const float* Wqs = (const float*)d_in[2];
  const float* Wqt = (const float*)d_in[3];
  const float* Wks = (const float*)d_in[4];
  const float* Wkt = (const float*)d_in[5];
  const float* Wvs = (const float*)d_in[6];
  const float* Wvt = (const float*)d_in[7];
  const float* rpb = (const float*)d_in[8];
  const float* pw  = (const float*)d_in[9];
  const float* pb  = (const float*)d_in[10];
  float* out = (float*)d_out;

  char* ws = (char*)d_ws;
  size_t off = 0;
  float* t_vec = (float*)(ws + off); off += (size_t)3*BATCH*DIM*4;
  short* Xb    = (short*)(ws + off); off += (size_t)MROWS*DIM*2;
  short* Wt    = (short*)(ws + off); off += (size_t)4*DIM*DIM*2;      // [Wqs^T, Wks^T, Wvs^T, proj^T]
  short* QKVb  = (short*)(ws + off); off += (size_t)3*MROWS*DIM*2;
  short* Ob    = (short*)(ws + off); off += (size_t)MROWS*DIM*2;
  // total ~53 MB

  cvt_bf16_kernel<<<2352, 256, 0, stream>>>(x_s, Xb, MROWS*DIM/8);
  wtrans_kernel<<<dim3(24,24,4), dim3(32,8), 0, stream>>>(Wqs, Wks, Wvs, pw, Wt);
  tvec_kernel<<<dim3(3,BATCH), 256, 0, stream>>>(x_t, Wqt, Wkt, Wvt, t_vec);
  gemm_kernel<0><<<dim3(6,49,3), 256, 0, stream>>>(Xb, Wt, t_vec, QKVb, nullptr);
  attn_kernel<<<dim3(13,NH,BATCH), 256, 0, stream>>>(QKVb,
                                                     QKVb + (size_t)MROWS*DIM,
                                                     QKVb + (size_t)2*MROWS*DIM,
                                                     rpb, Ob);
  gemm_kernel<1><<<dim3(6,49,1), 256, 0, stream>>>(Ob, Wt + (size_t)3*DIM*DIM, pb, nullptr, out);
}

// Round 2
// 192.276 us; speedup vs baseline: 1.3158x; 1.3158x over previous
//
#include <hip/hip_runtime.h>
#include <stdint.h>

#define DIM 768
#define NP  784
#define NH  12
#define HD  64
#define BATCH 8
#define MROWS (BATCH*NP)   // 6272
#define MPAD 832           // 13*64

using bf16x8 = __attribute__((ext_vector_type(8))) short;
using bf16x4 = __attribute__((ext_vector_type(4))) short;
using f32x4  = __attribute__((ext_vector_type(4))) float;

__device__ __forceinline__ short f2bf(float f) {
  union { float f; uint32_t u; } c; c.f = f;
  uint32_t u = c.u;
  u += 0x7FFFu + ((u >> 16) & 1u);   // RNE
  return (short)(u >> 16);
}

__device__ __forceinline__ void gld_lds16(const void* g, void* l) {
  __builtin_amdgcn_global_load_lds((const __attribute__((address_space(1))) uint32_t*)g,
                                   (__attribute__((address_space(3))) uint32_t*)l,
                                   16, 0, 0);
}

// ---------------- prep: x_s -> bf16 ----------------
__global__ __launch_bounds__(256) void cvt_bf16_kernel(const float* __restrict__ src,
                                                       short* __restrict__ dst, int n8) {
  int i = blockIdx.x * 256 + threadIdx.x;
  if (i >= n8) return;
  const float4* s = (const float4*)src;
  float4 a = s[2*i], b = s[2*i+1];
  bf16x8 o;
  o[0]=f2bf(a.x); o[1]=f2bf(a.y); o[2]=f2bf(a.z); o[3]=f2bf(a.w);
  o[4]=f2bf(b.x); o[5]=f2bf(b.y); o[6]=f2bf(b.z); o[7]=f2bf(b.w);
  ((bf16x8*)dst)[i] = o;
}

// ---------------- prep: W[k][n] -> Wt[n][k] bf16 (4 matrices) ----------------
__global__ __launch_bounds__(256) void wtrans_kernel(const float* __restrict__ w0,
                                                     const float* __restrict__ w1,
                                                     const float* __restrict__ w2,
                                                     const float* __restrict__ w3,
                                                     short* __restrict__ dst) {
  __shared__ float tile[32][33];
  const int z = blockIdx.z;
  const float* src = (z==0) ? w0 : (z==1) ? w1 : (z==2) ? w2 : w3;
  short* d = dst + (size_t)z * DIM * DIM;
  const int n0 = blockIdx.x*32, k0 = blockIdx.y*32;
  const int tx = threadIdx.x, ty = threadIdx.y;  // (32,8)
#pragma unroll
  for (int i=0;i<4;i++) tile[ty+i*8][tx] = src[(size_t)(k0+ty+i*8)*DIM + n0+tx];
  __syncthreads();
#pragma unroll
  for (int i=0;i<4;i++) d[(size_t)(n0+ty+i*8)*DIM + k0+tx] = f2bf(tile[tx][ty+i*8]);
}

// ---------------- prep: t[z][b][d] = x_t[b] @ Wt_z ----------------
__global__ __launch_bounds__(256) void tvec_kernel(const float* __restrict__ x_t,
                                                   const float* __restrict__ wq,
                                                   const float* __restrict__ wk,
                                                   const float* __restrict__ wv,
                                                   float* __restrict__ t) {
  const int z = blockIdx.x, b = blockIdx.y, d = threadIdx.x;
  const float* w = (z==0) ? wq : (z==1) ? wk : wv;
  const float* xt = x_t + (size_t)b * DIM;
  float a0=0.f, a1=0.f, a2=0.f;
  for (int k=0;k<DIM;k++) {
    float xv = xt[k];
    const float* wr = w + (size_t)k*DIM + d;
    a0 += xv * wr[0];
    a1 += xv * wr[256];
    a2 += xv * wr[512];
  }
  float* o = t + ((size_t)z*BATCH + b) * DIM;
  o[d]=a0; o[d+256]=a1; o[d+512]=a2;
}

// ---------------- GEMM: C[m][n] = A[m][k] * Bt[n][k]  (bf16 in, f32 acc) ----------------
template<int MODE>
__global__ __launch_bounds__(256) void gemm_kernel(const short* __restrict__ A,
                                                   const short* __restrict__ Bw,
                                                   const float* __restrict__ aux,
                                                   short* __restrict__ outb,
                                                   float* __restrict__ outf) {
  __shared__ short As[128*32];
  __shared__ short Bs[128*32];
  const int bx = blockIdx.x, by = blockIdx.y, z = blockIdx.z;
  const short* Bz = Bw + (size_t)z * DIM * DIM;
  const int tid = threadIdx.x, w = tid>>6, lane = tid&63;
  const int wr = w>>1, wc = w&1, ln15 = lane&15, lg = lane>>4;
  const int m0 = by*128, n0 = bx*128;

  f32x4 acc[4][4] = {};

  for (int kt=0; kt<24; ++kt) {
    const int k0 = kt*32;
    __syncthreads();
#pragma unroll
    for (int i=0;i<2;i++) {
      const int inst = w*2 + i;
      const int off  = inst*1024 + lane*16;
      const int row  = off >> 6;
      const int ce   = (off & 63) >> 1;
      gld_lds16(A  + (size_t)(m0+row)*DIM + k0 + ce, (char*)As + (size_t)inst*1024);
      gld_lds16(Bz + (size_t)(n0+row)*DIM + k0 + ce, (char*)Bs + (size_t)inst*1024);
    }
    __syncthreads();
    bf16x8 af[4], bfr[4];
#pragma unroll
    for (int mi=0;mi<4;mi++) af[mi]  = *(const bf16x8*)&As[(wr*64+mi*16+ln15)*32 + lg*8];
#pragma unroll
    for (int ni=0;ni<4;ni++) bfr[ni] = *(const bf16x8*)&Bs[(wc*64+ni*16+ln15)*32 + lg*8];
#pragma unroll
    for (int mi=0;mi<4;mi++)
#pragma unroll
      for (int ni=0;ni<4;ni++)
        acc[mi][ni] = __builtin_amdgcn_mfma_f32_16x16x32_bf16(af[mi], bfr[ni], acc[mi][ni], 0,0,0);
  }

  if (MODE == 0) {
    short* Oz = outb + (size_t)z * MROWS * DIM;
    const float scl = (z==0) ? 0.125f : 1.0f;
#pragma unroll
    for (int mi=0;mi<4;mi++) {
#pragma unroll
      for (int j=0;j<4;j++) {
        const int r  = m0 + wr*64 + mi*16 + lg*4 + j;
        const int bb = r / NP;
        const float* tv = aux + ((size_t)z*BATCH + bb) * DIM;
#pragma unroll
        for (int ni=0;ni<4;ni++) {
          const int gcol = n0 + wc*64 + ni*16 + ln15;
          Oz[(size_t)r*DIM + gcol] = f2bf((acc[mi][ni][j] + tv[gcol]) * scl);
        }
      }
    }
  } else {
#pragma unroll
    for (int mi=0;mi<4;mi++)
#pragma unroll
      for (int j=0;j<4;j++) {
        const int r = m0 + wr*64 + mi*16 + lg*4 + j;
#pragma unroll
        for (int ni=0;ni<4;ni++) {
          const int gcol = n0 + wc*64 + ni*16 + ln15;
          outf[(size_t)r*DIM + gcol] = acc[mi][ni][j] + aux[gcol];
        }
      }
  }
}

// ---------------- prep: K -> Kt[b][h][m_pad][64], V -> Vt[b][h][d][m_pad] ----------------
__global__ __launch_bounds__(256) void kvprep_kernel(const short* __restrict__ Kb,
                                                     const short* __restrict__ Vb,
                                                     short* __restrict__ Kt,
                                                     short* __restrict__ Vt) {
  __shared__ short lv[64][80];   // stride 80 elems: 16B-aligned rows, conflict-free read phase
  const int mt = blockIdx.x, h = blockIdx.y, b = blockIdx.z;
  const int m0 = mt*64, tid = threadIdx.x;
  const size_t bh = (size_t)(b*NH + h);
  const int r8 = tid >> 3, d0 = (tid & 7) * 8;
#pragma unroll
  for (int i = 0; i < 2; ++i) {
    const int r = i*32 + r8;
    const int m = m0 + r;
    bf16x8 kv = {}, vv = {};
    if (m < NP) {
      kv = *(const bf16x8*)(Kb + ((size_t)(b*NP + m))*DIM + h*HD + d0);
      vv = *(const bf16x8*)(Vb + ((size_t)(b*NP + m))*DIM + h*HD + d0);
    }
    *(bf16x8*)(Kt + (bh*MPAD + m0 + r)*HD + d0) = kv;
    *(bf16x8*)&lv[r][d0] = vv;
  }
  __syncthreads();
  const int d = tid & 63, mc = tid >> 6;
  bf16x8 a = {}, c = {};
#pragma unroll
  for (int j = 0; j < 8; ++j) { a[j] = lv[mc*16 + j][d]; c[j] = lv[mc*16 + 8 + j][d]; }
  short* vo = Vt + (bh*HD + d)*MPAD + m0 + mc*16;
  *(bf16x8*)vo = a;
  *(bf16x8*)(vo + 8) = c;
}

// ---------------- flash attention v2: KVBLK=64, double-buffered swizzled LDS ----------------
__global__ __launch_bounds__(256) void attn2_kernel(const short* __restrict__ Qb,
                                                    const short* __restrict__ Kt,
                                                    const short* __restrict__ Vt,
                                                    const float* __restrict__ rpb,
                                                    short* __restrict__ Ob) {
  __shared__ short kt[2][4096];    // K tile [64 m][64 d], rows XOR-swizzled (byte ^= (row&7)<<4)
  __shared__ short vt[2][4096];    // V^T tile [64 d][64 m], same swizzle
  __shared__ float bias_ext[112];
  __shared__ short msum[MPAD];
  const int qt = blockIdx.x, h = blockIdx.y, b = blockIdx.z;
  const int q0 = qt*64, tid = threadIdx.x, w = tid >> 6, lane = tid & 63;
  const int ln15 = lane & 15, lg = lane >> 4;

  if (tid < 109) bias_ext[tid + 2] = rpb[(tid/55)*(55*NH) + (tid%55)*NH + h];
  if (tid == 109) { bias_ext[0] = 0.f; bias_ext[1] = 0.f; bias_ext[111] = 0.f; }
  for (int i = tid; i < MPAD; i += 256) msum[i] = (short)(i/28 + i%28);

  const bool active = (q0 + w*16) < NP;
  const int q_idx = q0 + w*16 + ln15;
  bf16x8 qf0 = {}, qf1 = {};
  if (active) {
    const short* qp = Qb + ((size_t)(b*NP) + q_idx)*DIM + h*HD + lg*8;
    qf0 = *(const bf16x8*)qp;
    qf1 = *(const bf16x8*)(qp + 32);
  }
  const int qs = q_idx/28 + q_idx%28;

  // staging source pointers (pre-swizzled global addresses; LDS dest is linear)
  const int lr = lane >> 3, lc = lane & 7;
  const int swe = (lc ^ lr) << 3;            // element offset after (row&7)<<4 byte-XOR
  const size_t bh = (size_t)(b*NH + h);
  const short* kp0 = Kt + (bh*MPAD + (size_t)(w*8 + lr))*HD + swe;
  const short* kp1 = kp0 + 32*HD;            // rows +32
  const short* vp0 = Vt + (bh*HD + (size_t)(w*8 + lr))*MPAD + swe;
  const short* vp1 = vp0 + 32*MPAD;          // d +32

#define STAGE4(BUF) { \
    char* kb_ = (char*)kt[BUF]; char* vb_ = (char*)vt[BUF]; \
    gld_lds16(kp0, kb_ + w*1024); \
    gld_lds16(kp1, kb_ + (w+4)*1024); \
    gld_lds16(vp0, vb_ + w*1024); \
    gld_lds16(vp1, vb_ + (w+4)*1024); \
    kp0 += 64*HD; kp1 += 64*HD; vp0 += 64; vp1 += 64; }

  float m_run = -3.0e38f, l_run = 0.f;
  f32x4 o0 = {}, o1 = {}, o2 = {}, o3 = {};

  STAGE4(0)

  for (int t = 0; t < 13; ++t) {
    const int cur = t & 1;
    const int m0 = t * 64;
    __syncthreads();               // staged buf `cur` ready; prev reads of other buf done
    if (t < 12) STAGE4(cur^1)
    if (active) {
      const char* kb = (const char*)kt[cur];
      const int sw = (ln15 & 7) << 4;
      f32x4 s[4];
#pragma unroll
      for (int mc = 0; mc < 4; ++mc) {
        const int rb = (mc*16 + ln15) * 128;
        bf16x8 kf0 = *(const bf16x8*)(kb + rb + ((lg*16) ^ sw));
        bf16x8 kf1 = *(const bf16x8*)(kb + rb + ((lg*16 + 64) ^ sw));
        f32x4 acc = {};
        acc = __builtin_amdgcn_mfma_f32_16x16x32_bf16(kf0, qf0, acc, 0,0,0);
        acc = __builtin_amdgcn_mfma_f32_16x16x32_bf16(kf1, qf1, acc, 0,0,0);
        s[mc] = acc;
      }
      // rel-pos bias via 1-D tables
#pragma unroll
      for (int mc = 0; mc < 4; ++mc) {
        const int mb = m0 + mc*16 + lg*4;
        bf16x4 ms4 = *(const bf16x4*)&msum[mb];
#pragma unroll
        for (int j = 0; j < 4; ++j)
          s[mc][j] += bias_ext[qs - (int)ms4[j] + 56];
      }
      if (m0 + 64 > NP) {          // mask padded rows (last tile only)
#pragma unroll
        for (int mc = 0; mc < 4; ++mc)
#pragma unroll
          for (int j = 0; j < 4; ++j)
            if (m0 + mc*16 + lg*4 + j >= NP) s[mc][j] = -1e30f;
      }
      // online softmax over 16 scores/lane + lg-group reduce
      float tm = s[0][0];
#pragma unroll
      for (int mc = 0; mc < 4; ++mc)
#pragma unroll
        for (int j = 0; j < 4; ++j) tm = fmaxf(tm, s[mc][j]);
      tm = fmaxf(tm, __shfl_xor(tm, 16));
      tm = fmaxf(tm, __shfl_xor(tm, 32));
      const float m_new = fmaxf(m_run, tm);
      const float f = __expf(m_run - m_new);
      float ts = 0.f;
#pragma unroll
      for (int mc = 0; mc < 4; ++mc)
#pragma unroll
        for (int j = 0; j < 4; ++j) { float p = __expf(s[mc][j] - m_new); s[mc][j] = p; ts += p; }
      ts += __shfl_xor(ts, 16);
      ts += __shfl_xor(ts, 32);
      l_run = l_run * f + ts;
      m_run = m_new;
      o0 *= f; o1 *= f; o2 *= f; o3 *= f;
      bf16x4 pb[4];
#pragma unroll
      for (int mc = 0; mc < 4; ++mc) {
        pb[mc][0] = f2bf(s[mc][0]); pb[mc][1] = f2bf(s[mc][1]);
        pb[mc][2] = f2bf(s[mc][2]); pb[mc][3] = f2bf(s[mc][3]);
      }
      const char* vb = (const char*)vt[cur];
#pragma unroll
      for (int mc = 0; mc < 4; ++mc) {
        const int ib = (mc*32 + lg*8) ^ sw;
        bf16x4 vf0 = *(const bf16x4*)(vb + (0*16+ln15)*128 + ib);
        bf16x4 vf1 = *(const bf16x4*)(vb + (1*16+ln15)*128 + ib);
        bf16x4 vf2 = *(const bf16x4*)(vb + (2*16+ln15)*128 + ib);
        bf16x4 vf3 = *(const bf16x4*)(vb + (3*16+ln15)*128 + ib);
        o0 = __builtin_amdgcn_mfma_f32_16x16x16bf16_1k(vf0, pb[mc], o0, 0,0,0);
        o1 = __builtin_amdgcn_mfma_f32_16x16x16bf16_1k(vf1, pb[mc], o1, 0,0,0);
        o2 = __builtin_amdgcn_mfma_f32_16x16x16bf16_1k(vf2, pb[mc], o2, 0,0,0);
        o3 = __builtin_amdgcn_mfma_f32_16x16x16bf16_1k(vf3, pb[mc], o3, 0,0,0);
      }
    }
  }
#undef STAGE4

  if (active) {
    const float inv = 1.0f / l_run;
    short* op = Ob + ((size_t)(b*NP) + q_idx)*DIM + h*HD + lg*4;
    bf16x4 ov;
    ov[0]=f2bf(o0[0]*inv); ov[1]=f2bf(o0[1]*inv); ov[2]=f2bf(o0[2]*inv); ov[3]=f2bf(o0[3]*inv);
    *(bf16x4*)(op + 0*16) = ov;
    ov[0]=f2bf(o1[0]*inv); ov[1]=f2bf(o1[1]*inv); ov[2]=f2bf(o1[2]*inv); ov[3]=f2bf(o1[3]*inv);
    *(bf16x4*)(op + 1*16) = ov;
    ov[0]=f2bf(o2[0]*inv); ov[1]=f2bf(o2[1]*inv); ov[2]=f2bf(o2[2]*inv); ov[3]=f2bf(o2[3]*inv);
    *(bf16x4*)(op + 2*16) = ov;
    ov[0]=f2bf(o3[0]*inv); ov[1]=f2bf(o3[1]*inv); ov[2]=f2bf(o3[2]*inv); ov[3]=f2bf(o3[3]*inv);
    *(bf16x4*)(op + 3*16) = ov;
  }
}

extern "C" void kernel_launch(void* const* d_in, const int* in_sizes, int n_in,
                              void* d_out, int out_size, void* d_ws, size_t ws_size,
                              hipStream_t stream) {
  const float* x_s = (const float*)d_in[0];
  const float* x_t = (const float*)d_in[1];
  const float* Wqs = (const float*)d_in[2];
  const float* Wqt = (const float*)d_in[3];
  const float* Wks = (const float*)d_in[4];
  const float* Wkt = (const float*)d_in[5];
  const float* Wvs = (const float*)d_in[6];
  const float* Wvt = (const float*)d_in[7];
  const float* rpb = (const float*)d_in[8];
  const float* pw  = (const float*)d_in[9];
  const float* pb  = (const float*)d_in[10];
  float* out = (float*)d_out;

  char* ws = (char*)d_ws;
  size_t off = 0;
  float* t_vec = (float*)(ws + off); off += (size_t)3*BATCH*DIM*4;
  short* Wt    = (short*)(ws + off); off += (size_t)4*DIM*DIM*2;
  short* QKVb  = (short*)(ws + off); off += (size_t)3*MROWS*DIM*2;
  short* Ob    = (short*)(ws + off); off += (size_t)MROWS*DIM*2;
  short* Xb    = (short*)(ws + off);                               // dead after gemm<0>
  short* Kt    = (short*)(ws + off); off += (size_t)BATCH*NH*MPAD*HD*2;  // overlays Xb
  short* Vt    = (short*)(ws + off); off += (size_t)BATCH*NH*MPAD*HD*2;
  // total ~64 MB

  cvt_bf16_kernel<<<2352, 256, 0, stream>>>(x_s, Xb, MROWS*DIM/8);
  wtrans_kernel<<<dim3(24,24,4), dim3(32,8), 0, stream>>>(Wqs, Wks, Wvs, pw, Wt);
  tvec_kernel<<<dim3(3,BATCH), 256, 0, stream>>>(x_t, Wqt, Wkt, Wvt, t_vec);
  gemm_kernel<0><<<dim3(6,49,3), 256, 0, stream>>>(Xb, Wt, t_vec, QKVb, nullptr);
  kvprep_kernel<<<dim3(13,NH,BATCH), 256, 0, stream>>>(QKVb + (size_t)MROWS*DIM,
                                                       QKVb + (size_t)2*MROWS*DIM,
                                                       Kt, Vt);
  attn2_kernel<<<dim3(13,NH,BATCH), 256, 0, stream>>>(QKVb, Kt, Vt, rpb, Ob);
  gemm_kernel<1><<<dim3(6,49,1), 256, 0, stream>>>(Ob, Wt + (size_t)3*DIM*DIM, pb, nullptr, out);
}

// Round 3
// 139.534 us; speedup vs baseline: 1.8131x; 1.3780x over previous
//
#include <hip/hip_runtime.h>
#include <stdint.h>

#define DIM 768
#define NP  784
#define NH  12
#define HD  64
#define BATCH 8
#define MROWS (BATCH*NP)   // 6272
#define MPAD 832           // 13*64
#define NCHUNK 32
#define KCH 24             // 768/32

using bf16x8 = __attribute__((ext_vector_type(8))) short;
using bf16x4 = __attribute__((ext_vector_type(4))) short;
using f32x4  = __attribute__((ext_vector_type(4))) float;

__device__ __forceinline__ short f2bf(float f) {
  union { float f; uint32_t u; } c; c.f = f;
  uint32_t u = c.u;
  u += 0x7FFFu + ((u >> 16) & 1u);   // RNE
  return (short)(u >> 16);
}

__device__ __forceinline__ void gld_lds16(const void* g, void* l) {
  __builtin_amdgcn_global_load_lds((const __attribute__((address_space(1))) uint32_t*)g,
                                   (__attribute__((address_space(3))) uint32_t*)l,
                                   16, 0, 0);
}

// ---------------- prep: x_s -> bf16 ----------------
__global__ __launch_bounds__(256) void cvt_bf16_kernel(const float* __restrict__ src,
                                                       short* __restrict__ dst, int n8) {
  int i = blockIdx.x * 256 + threadIdx.x;
  if (i >= n8) return;
  const float4* s = (const float4*)src;
  float4 a = s[2*i], b = s[2*i+1];
  bf16x8 o;
  o[0]=f2bf(a.x); o[1]=f2bf(a.y); o[2]=f2bf(a.z); o[3]=f2bf(a.w);
  o[4]=f2bf(b.x); o[5]=f2bf(b.y); o[6]=f2bf(b.z); o[7]=f2bf(b.w);
  ((bf16x8*)dst)[i] = o;
}

// ---------------- prep: W[k][n] -> Wt[n][k] bf16 (4 matrices) ----------------
__global__ __launch_bounds__(256) void wtrans_kernel(const float* __restrict__ w0,
                                                     const float* __restrict__ w1,
                                                     const float* __restrict__ w2,
                                                     const float* __restrict__ w3,
                                                     short* __restrict__ dst) {
  __shared__ float tile[32][33];
  const int z = blockIdx.z;
  const float* src = (z==0) ? w0 : (z==1) ? w1 : (z==2) ? w2 : w3;
  short* d = dst + (size_t)z * DIM * DIM;
  const int n0 = blockIdx.x*32, k0 = blockIdx.y*32;
  const int tx = threadIdx.x, ty = threadIdx.y;  // (32,8)
#pragma unroll
  for (int i=0;i<4;i++) tile[ty+i*8][tx] = src[(size_t)(k0+ty+i*8)*DIM + n0+tx];
  __syncthreads();
#pragma unroll
  for (int i=0;i<4;i++) d[(size_t)(n0+ty+i*8)*DIM + k0+tx] = f2bf(tile[tx][ty+i*8]);
}

// ---------------- prep: split-k GEMV partials: part[z][kc][b][d] ----------------
__global__ __launch_bounds__(256) void tvec1_kernel(const float* __restrict__ x_t,
                                                    const float* __restrict__ wq,
                                                    const float* __restrict__ wk,
                                                    const float* __restrict__ wv,
                                                    float* __restrict__ part) {
  const int z = blockIdx.x, kc = blockIdx.y;
  const float* w = (z==0) ? wq : (z==1) ? wk : wv;
  const int d = threadIdx.x;
  __shared__ float xs[BATCH][KCH];
  if (threadIdx.x < BATCH*KCH)
    xs[threadIdx.x / KCH][threadIdx.x % KCH] =
        x_t[(size_t)(threadIdx.x / KCH)*DIM + kc*KCH + threadIdx.x % KCH];
  __syncthreads();
  float a0[BATCH] = {}, a1[BATCH] = {}, a2[BATCH] = {};
#pragma unroll 4
  for (int k = 0; k < KCH; ++k) {
    const float* wr = w + (size_t)(kc*KCH + k)*DIM + d;
    float w0 = wr[0], w1 = wr[256], w2 = wr[512];
#pragma unroll
    for (int b = 0; b < BATCH; ++b) {
      float xv = xs[b][k];
      a0[b] += xv*w0; a1[b] += xv*w1; a2[b] += xv*w2;
    }
  }
#pragma unroll
  for (int b = 0; b < BATCH; ++b) {
    float* p = part + (((size_t)z*NCHUNK + kc)*BATCH + b)*DIM + d;
    p[0] = a0[b]; p[256] = a1[b]; p[512] = a2[b];
  }
}

// ---------------- reduce partials -> t[z][b][d] ----------------
__global__ __launch_bounds__(256) void tvec2_kernel(const float* __restrict__ part,
                                                    float* __restrict__ t) {
  const int i = blockIdx.x*256 + threadIdx.x;   // 3*8*768 = 18432
  if (i >= 3*BATCH*DIM) return;
  const int z = i / (BATCH*DIM), rem = i % (BATCH*DIM);
  float s = 0.f;
#pragma unroll 8
  for (int c = 0; c < NCHUNK; ++c)
    s += part[((size_t)z*NCHUNK + c)*BATCH*DIM + rem];
  t[i] = s;
}

// ---------------- GEMM: C[m][n] = A[m][k] * Bt[n][k]  (bf16 in, f32 acc) ----------------
// MODE 0: QKV — adds t-vec; z=0 -> Q (x0.125, std layout), z=1 -> Kt layout, z=2 -> Vt transposed
// MODE 1: proj — adds bias, stores f32
template<int MODE>
__global__ __launch_bounds__(256) void gemm_kernel(const short* __restrict__ A,
                                                   const short* __restrict__ Bw,
                                                   const float* __restrict__ aux,
                                                   short* __restrict__ outq,
                                                   short* __restrict__ outk,
                                                   short* __restrict__ outv,
                                                   float* __restrict__ outf) {
  __shared__ short As[128*32];
  __shared__ short Bs[128*32];
  const int bx = blockIdx.x, by = blockIdx.y, z = blockIdx.z;
  const short* Bz = Bw + (size_t)z * DIM * DIM;
  const int tid = threadIdx.x, w = tid>>6, lane = tid&63;
  const int wr = w>>1, wc = w&1, ln15 = lane&15, lg = lane>>4;
  const int m0 = by*128, n0 = bx*128;

  f32x4 acc[4][4] = {};

  for (int kt=0; kt<24; ++kt) {
    const int k0 = kt*32;
    __syncthreads();
#pragma unroll
    for (int i=0;i<2;i++) {
      const int inst = w*2 + i;
      const int off  = inst*1024 + lane*16;
      const int row  = off >> 6;
      const int ce   = (off & 63) >> 1;
      gld_lds16(A  + (size_t)(m0+row)*DIM + k0 + ce, (char*)As + (size_t)inst*1024);
      gld_lds16(Bz + (size_t)(n0+row)*DIM + k0 + ce, (char*)Bs + (size_t)inst*1024);
    }
    __syncthreads();
    bf16x8 af[4], bfr[4];
#pragma unroll
    for (int mi=0;mi<4;mi++) af[mi]  = *(const bf16x8*)&As[(wr*64+mi*16+ln15)*32 + lg*8];
#pragma unroll
    for (int ni=0;ni<4;ni++) bfr[ni] = *(const bf16x8*)&Bs[(wc*64+ni*16+ln15)*32 + lg*8];
#pragma unroll
    for (int mi=0;mi<4;mi++)
#pragma unroll
      for (int ni=0;ni<4;ni++)
        acc[mi][ni] = __builtin_amdgcn_mfma_f32_16x16x32_bf16(af[mi], bfr[ni], acc[mi][ni], 0,0,0);
  }

  if (MODE == 0) {
    const float scl = (z==0) ? 0.125f : 1.0f;
#pragma unroll
    for (int mi=0;mi<4;mi++) {
#pragma unroll
      for (int j=0;j<4;j++) {
        const int r  = m0 + wr*64 + mi*16 + lg*4 + j;
        const int bb = r / NP;
        const int m  = r - bb*NP;
        const float* tv = aux + ((size_t)z*BATCH + bb) * DIM;
        if (z == 0) {
#pragma unroll
          for (int ni=0;ni<4;ni++) {
            const int gcol = n0 + wc*64 + ni*16 + ln15;
            outq[(size_t)r*DIM + gcol] = f2bf((acc[mi][ni][j] + tv[gcol]) * scl);
          }
        } else if (z == 1) {
#pragma unroll
          for (int ni=0;ni<4;ni++) {
            const int gcol = n0 + wc*64 + ni*16 + ln15;
            const int h = gcol >> 6, d = gcol & 63;
            outk[((size_t)(bb*NH + h)*MPAD + m)*HD + d] = f2bf(acc[mi][ni][j] + tv[gcol]);
          }
        }
      }
      if (MODE == 0 && z == 2) {
        // transposed V store: one bf16x4 along m per (mi,ni)
        const int r0 = m0 + wr*64 + mi*16 + lg*4;
        const int bb = r0 / NP;
        const int m  = r0 - bb*NP;          // group of 4 never crosses batch (784%4==0)
        const float* tv = aux + ((size_t)2*BATCH + bb) * DIM;
#pragma unroll
        for (int ni=0;ni<4;ni++) {
          const int gcol = n0 + wc*64 + ni*16 + ln15;
          const int h = gcol >> 6, d = gcol & 63;
          const float tb = tv[gcol];
          bf16x4 ov;
          ov[0] = f2bf(acc[mi][ni][0] + tb);
          ov[1] = f2bf(acc[mi][ni][1] + tb);
          ov[2] = f2bf(acc[mi][ni][2] + tb);
          ov[3] = f2bf(acc[mi][ni][3] + tb);
          *(bf16x4*)&outv[((size_t)(bb*NH + h)*HD + d)*MPAD + m] = ov;
        }
      }
    }
  } else {
#pragma unroll
    for (int mi=0;mi<4;mi++)
#pragma unroll
      for (int j=0;j<4;j++) {
        const int r = m0 + wr*64 + mi*16 + lg*4 + j;
#pragma unroll
        for (int ni=0;ni<4;ni++) {
          const int gcol = n0 + wc*64 + ni*16 + ln15;
          outf[(size_t)r*DIM + gcol] = acc[mi][ni][j] + aux[gcol];
        }
      }
  }
}

// ---------------- flash attention v2: KVBLK=64, double-buffered swizzled LDS ----------------
__global__ __launch_bounds__(256) void attn2_kernel(const short* __restrict__ Qb,
                                                    const short* __restrict__ Kt,
                                                    const short* __restrict__ Vt,
                                                    const float* __restrict__ rpb,
                                                    short* __restrict__ Ob) {
  __shared__ short kt[2][4096];    // K tile [64 m][64 d], rows XOR-swizzled (byte ^= (row&7)<<4)
  __shared__ short vt[2][4096];    // V^T tile [64 d][64 m], same swizzle
  __shared__ float bias_ext[112];
  __shared__ short msum[MPAD];
  const int qt = blockIdx.x, h = blockIdx.y, b = blockIdx.z;
  const int q0 = qt*64, tid = threadIdx.x, w = tid >> 6, lane = tid & 63;
  const int ln15 = lane & 15, lg = lane >> 4;

  if (tid < 109) bias_ext[tid + 2] = rpb[(tid/55)*(55*NH) + (tid%55)*NH + h];
  if (tid == 109) { bias_ext[0] = 0.f; bias_ext[1] = 0.f; bias_ext[111] = 0.f; }
  for (int i = tid; i < MPAD; i += 256) msum[i] = (short)(i/28 + i%28);

  const bool active = (q0 + w*16) < NP;
  const int q_idx = q0 + w*16 + ln15;
  bf16x8 qf0 = {}, qf1 = {};
  if (active) {
    const short* qp = Qb + ((size_t)(b*NP) + q_idx)*DIM + h*HD + lg*8;
    qf0 = *(const bf16x8*)qp;
    qf1 = *(const bf16x8*)(qp + 32);
  }
  const int qs = q_idx/28 + q_idx%28;

  const int lr = lane >> 3, lc = lane & 7;
  const int swe = (lc ^ lr) << 3;
  const size_t bh = (size_t)(b*NH + h);
  const short* kp0 = Kt + (bh*MPAD + (size_t)(w*8 + lr))*HD + swe;
  const short* kp1 = kp0 + 32*HD;
  const short* vp0 = Vt + (bh*HD + (size_t)(w*8 + lr))*MPAD + swe;
  const short* vp1 = vp0 + 32*MPAD;

#define STAGE4(BUF) { \
    char* kb_ = (char*)kt[BUF]; char* vb_ = (char*)vt[BUF]; \
    gld_lds16(kp0, kb_ + w*1024); \
    gld_lds16(kp1, kb_ + (w+4)*1024); \
    gld_lds16(vp0, vb_ + w*1024); \
    gld_lds16(vp1, vb_ + (w+4)*1024); \
    kp0 += 64*HD; kp1 += 64*HD; vp0 += 64; vp1 += 64; }

  float m_run = -3.0e38f, l_run = 0.f;
  f32x4 o0 = {}, o1 = {}, o2 = {}, o3 = {};

  STAGE4(0)

  for (int t = 0; t < 13; ++t) {
    const int cur = t & 1;
    const int m0 = t * 64;
    __syncthreads();
    if (t < 12) STAGE4(cur^1)
    if (active) {
      const char* kb = (const char*)kt[cur];
      const int sw = (ln15 & 7) << 4;
      f32x4 s[4];
#pragma unroll
      for (int mc = 0; mc < 4; ++mc) {
        const int rb = (mc*16 + ln15) * 128;
        bf16x8 kf0 = *(const bf16x8*)(kb + rb + ((lg*16) ^ sw));
        bf16x8 kf1 = *(const bf16x8*)(kb + rb + ((lg*16 + 64) ^ sw));
        f32x4 acc = {};
        acc = __builtin_amdgcn_mfma_f32_16x16x32_bf16(kf0, qf0, acc, 0,0,0);
        acc = __builtin_amdgcn_mfma_f32_16x16x32_bf16(kf1, qf1, acc, 0,0,0);
        s[mc] = acc;
      }
#pragma unroll
      for (int mc = 0; mc < 4; ++mc) {
        const int mb = m0 + mc*16 + lg*4;
        bf16x4 ms4 = *(const bf16x4*)&msum[mb];
#pragma unroll
        for (int j = 0; j < 4; ++j)
          s[mc][j] += bias_ext[qs - (int)ms4[j] + 56];
      }
      if (m0 + 64 > NP) {
#pragma unroll
        for (int mc = 0; mc < 4; ++mc)
#pragma unroll
          for (int j = 0; j < 4; ++j)
            if (m0 + mc*16 + lg*4 + j >= NP) s[mc][j] = -1e30f;
      }
      float tm = s[0][0];
#pragma unroll
      for (int mc = 0; mc < 4; ++mc)
#pragma unroll
        for (int j = 0; j < 4; ++j) tm = fmaxf(tm, s[mc][j]);
      tm = fmaxf(tm, __shfl_xor(tm, 16));
      tm = fmaxf(tm, __shfl_xor(tm, 32));
      const float m_new = fmaxf(m_run, tm);
      const float f = __expf(m_run - m_new);
      float ts = 0.f;
#pragma unroll
      for (int mc = 0; mc < 4; ++mc)
#pragma unroll
        for (int j = 0; j < 4; ++j) { float p = __expf(s[mc][j] - m_new); s[mc][j] = p; ts += p; }
      ts += __shfl_xor(ts, 16);
      ts += __shfl_xor(ts, 32);
      l_run = l_run * f + ts;
      m_run = m_new;
      o0 *= f; o1 *= f; o2 *= f; o3 *= f;
      bf16x4 pb[4];
#pragma unroll
      for (int mc = 0; mc < 4; ++mc) {
        pb[mc][0] = f2bf(s[mc][0]); pb[mc][1] = f2bf(s[mc][1]);
        pb[mc][2] = f2bf(s[mc][2]); pb[mc][3] = f2bf(s[mc][3]);
      }
      const char* vb = (const char*)vt[cur];
#pragma unroll
      for (int mc = 0; mc < 4; ++mc) {
        const int ib = (mc*32 + lg*8) ^ sw;
        bf16x4 vf0 = *(const bf16x4*)(vb + (0*16+ln15)*128 + ib);
        bf16x4 vf1 = *(const bf16x4*)(vb + (1*16+ln15)*128 + ib);
        bf16x4 vf2 = *(const bf16x4*)(vb + (2*16+ln15)*128 + ib);
        bf16x4 vf3 = *(const bf16x4*)(vb + (3*16+ln15)*128 + ib);
        o0 = __builtin_amdgcn_mfma_f32_16x16x16bf16_1k(vf0, pb[mc], o0, 0,0,0);
        o1 = __builtin_amdgcn_mfma_f32_16x16x16bf16_1k(vf1, pb[mc], o1, 0,0,0);
        o2 = __builtin_amdgcn_mfma_f32_16x16x16bf16_1k(vf2, pb[mc], o2, 0,0,0);
        o3 = __builtin_amdgcn_mfma_f32_16x16x16bf16_1k(vf3, pb[mc], o3, 0,0,0);
      }
    }
  }
#undef STAGE4

  if (active) {
    const float inv = 1.0f / l_run;
    short* op = Ob + ((size_t)(b*NP) + q_idx)*DIM + h*HD + lg*4;
    bf16x4 ov;
    ov[0]=f2bf(o0[0]*inv); ov[1]=f2bf(o0[1]*inv); ov[2]=f2bf(o0[2]*inv); ov[3]=f2bf(o0[3]*inv);
    *(bf16x4*)(op + 0*16) = ov;
    ov[0]=f2bf(o1[0]*inv); ov[1]=f2bf(o1[1]*inv); ov[2]=f2bf(o1[2]*inv); ov[3]=f2bf(o1[3]*inv);
    *(bf16x4*)(op + 1*16) = ov;
    ov[0]=f2bf(o2[0]*inv); ov[1]=f2bf(o2[1]*inv); ov[2]=f2bf(o2[2]*inv); ov[3]=f2bf(o2[3]*inv);
    *(bf16x4*)(op + 2*16) = ov;
    ov[0]=f2bf(o3[0]*inv); ov[1]=f2bf(o3[1]*inv); ov[2]=f2bf(o3[2]*inv); ov[3]=f2bf(o3[3]*inv);
    *(bf16x4*)(op + 3*16) = ov;
  }
}

extern "C" void kernel_launch(void* const* d_in, const int* in_sizes, int n_in,
                              void* d_out, int out_size, void* d_ws, size_t ws_size,
                              hipStream_t stream) {
  const float* x_s = (const float*)d_in[0];
  const float* x_t = (const float*)d_in[1];
  const float* Wqs = (const float*)d_in[2];
  const float* Wqt = (const float*)d_in[3];
  const float* Wks = (const float*)d_in[4];
  const float* Wkt = (const float*)d_in[5];
  const float* Wvs = (const float*)d_in[6];
  const float* Wvt = (const float*)d_in[7];
  const float* rpb = (const float*)d_in[8];
  const float* pw  = (const float*)d_in[9];
  const float* pb  = (const float*)d_in[10];
  float* out = (float*)d_out;

  char* ws = (char*)d_ws;
  size_t off = 0;
  float* t_part = (float*)(ws + off); off += (size_t)3*NCHUNK*BATCH*DIM*4;
  float* t_vec  = (float*)(ws + off); off += (size_t)3*BATCH*DIM*4;
  short* Wt     = (short*)(ws + off); off += (size_t)4*DIM*DIM*2;
  short* Qb     = (short*)(ws + off); off += (size_t)MROWS*DIM*2;
  short* Ob     = (short*)(ws + off); off += (size_t)MROWS*DIM*2;
  short* Xb     = (short*)(ws + off); off += (size_t)MROWS*DIM*2;
  short* Kt     = (short*)(ws + off); off += (size_t)BATCH*NH*MPAD*HD*2;
  short* Vt     = (short*)(ws + off); off += (size_t)BATCH*NH*MPAD*HD*2;
  // total ~57 MB

  cvt_bf16_kernel<<<2352, 256, 0, stream>>>(x_s, Xb, MROWS*DIM/8);
  wtrans_kernel<<<dim3(24,24,4), dim3(32,8), 0, stream>>>(Wqs, Wks, Wvs, pw, Wt);
  tvec1_kernel<<<dim3(3,NCHUNK), 256, 0, stream>>>(x_t, Wqt, Wkt, Wvt, t_part);
  tvec2_kernel<<<72, 256, 0, stream>>>(t_part, t_vec);
  gemm_kernel<0><<<dim3(6,49,3), 256, 0, stream>>>(Xb, Wt, t_vec, Qb, Kt, Vt, nullptr);
  attn2_kernel<<<dim3(13,NH,BATCH), 256, 0, stream>>>(Qb, Kt, Vt, rpb, Ob);
  gemm_kernel<1><<<dim3(6,49,1), 256, 0, stream>>>(Ob, Wt + (size_t)3*DIM*DIM, pb,
                                                   nullptr, nullptr, nullptr, out);
}

// Round 4
// 139.420 us; speedup vs baseline: 1.8146x; 1.0008x over previous
//
#include <hip/hip_runtime.h>
#include <hip/hip_bf16.h>
#include <stdint.h>

#define DIM 768
#define NP  784
#define NH  12
#define HD  64
#define BATCH 8
#define MROWS (BATCH*NP)   // 6272
#define MPAD 832           // 13*64
#define NCHUNK 32
#define KCH 24             // 768/32
#define L2E 1.4426950408889634f

using bf16x8 = __attribute__((ext_vector_type(8))) short;
using bf16x4 = __attribute__((ext_vector_type(4))) short;
using f32x4  = __attribute__((ext_vector_type(4))) float;

__device__ __forceinline__ short f2bf(float f) {
  union { float f; uint32_t u; } c; c.f = f;
  uint32_t u = c.u;
  u += 0x7FFFu + ((u >> 16) & 1u);   // RNE
  return (short)(u >> 16);
}

// native path: compiler emits v_cvt_pk_bf16_f32 for adjacent pairs (m240)
__device__ __forceinline__ short bfr(float x) {
  union { __hip_bfloat16 b; short s; } u;
  u.b = __float2bfloat16(x);
  return u.s;
}

__device__ __forceinline__ void gld_lds16(const void* g, void* l) {
  __builtin_amdgcn_global_load_lds((const __attribute__((address_space(1))) uint32_t*)g,
                                   (__attribute__((address_space(3))) uint32_t*)l,
                                   16, 0, 0);
}

// ---------------- prep: x_s -> bf16 ----------------
__global__ __launch_bounds__(256) void cvt_bf16_kernel(const float* __restrict__ src,
                                                       short* __restrict__ dst, int n8) {
  int i = blockIdx.x * 256 + threadIdx.x;
  if (i >= n8) return;
  const float4* s = (const float4*)src;
  float4 a = s[2*i], b = s[2*i+1];
  bf16x8 o;
  o[0]=f2bf(a.x); o[1]=f2bf(a.y); o[2]=f2bf(a.z); o[3]=f2bf(a.w);
  o[4]=f2bf(b.x); o[5]=f2bf(b.y); o[6]=f2bf(b.z); o[7]=f2bf(b.w);
  ((bf16x8*)dst)[i] = o;
}

// ---------------- prep: W[k][n] -> Wt[n][k] bf16 (4 matrices) ----------------
__global__ __launch_bounds__(256) void wtrans_kernel(const float* __restrict__ w0,
                                                     const float* __restrict__ w1,
                                                     const float* __restrict__ w2,
                                                     const float* __restrict__ w3,
                                                     short* __restrict__ dst) {
  __shared__ float tile[32][33];
  const int z = blockIdx.z;
  const float* src = (z==0) ? w0 : (z==1) ? w1 : (z==2) ? w2 : w3;
  short* d = dst + (size_t)z * DIM * DIM;
  const int n0 = blockIdx.x*32, k0 = blockIdx.y*32;
  const int tx = threadIdx.x, ty = threadIdx.y;  // (32,8)
#pragma unroll
  for (int i=0;i<4;i++) tile[ty+i*8][tx] = src[(size_t)(k0+ty+i*8)*DIM + n0+tx];
  __syncthreads();
#pragma unroll
  for (int i=0;i<4;i++) d[(size_t)(n0+ty+i*8)*DIM + k0+tx] = f2bf(tile[tx][ty+i*8]);
}

// ---------------- prep: split-k GEMV partials: part[z][kc][b][d] ----------------
__global__ __launch_bounds__(256) void tvec1_kernel(const float* __restrict__ x_t,
                                                    const float* __restrict__ wq,
                                                    const float* __restrict__ wk,
                                                    const float* __restrict__ wv,
                                                    float* __restrict__ part) {
  const int z = blockIdx.x, kc = blockIdx.y;
  const float* w = (z==0) ? wq : (z==1) ? wk : wv;
  const int d = threadIdx.x;
  __shared__ float xs[BATCH][KCH];
  if (threadIdx.x < BATCH*KCH)
    xs[threadIdx.x / KCH][threadIdx.x % KCH] =
        x_t[(size_t)(threadIdx.x / KCH)*DIM + kc*KCH + threadIdx.x % KCH];
  __syncthreads();
  float a0[BATCH] = {}, a1[BATCH] = {}, a2[BATCH] = {};
#pragma unroll 4
  for (int k = 0; k < KCH; ++k) {
    const float* wr = w + (size_t)(kc*KCH + k)*DIM + d;
    float w0 = wr[0], w1 = wr[256], w2 = wr[512];
#pragma unroll
    for (int b = 0; b < BATCH; ++b) {
      float xv = xs[b][k];
      a0[b] += xv*w0; a1[b] += xv*w1; a2[b] += xv*w2;
    }
  }
#pragma unroll
  for (int b = 0; b < BATCH; ++b) {
    float* p = part + (((size_t)z*NCHUNK + kc)*BATCH + b)*DIM + d;
    p[0] = a0[b]; p[256] = a1[b]; p[512] = a2[b];
  }
}

// ---------------- reduce partials -> t[z][b][d] ----------------
__global__ __launch_bounds__(256) void tvec2_kernel(const float* __restrict__ part,
                                                    float* __restrict__ t) {
  const int i = blockIdx.x*256 + threadIdx.x;   // 3*8*768 = 18432
  if (i >= 3*BATCH*DIM) return;
  const int z = i / (BATCH*DIM), rem = i % (BATCH*DIM);
  float s = 0.f;
#pragma unroll 8
  for (int c = 0; c < NCHUNK; ++c)
    s += part[((size_t)z*NCHUNK + c)*BATCH*DIM + rem];
  t[i] = s;
}

// ---------------- GEMM: C[m][n] = A[m][k] * Bt[n][k]  (bf16 in, f32 acc) ----------------
// MODE 0: QKV — adds t-vec; z=0 -> Q (x 0.125*log2e, std layout), z=1 -> Kt, z=2 -> Vt transposed
// MODE 1: proj — adds bias, stores f32
template<int MODE>
__global__ __launch_bounds__(256) void gemm_kernel(const short* __restrict__ A,
                                                   const short* __restrict__ Bw,
                                                   const float* __restrict__ aux,
                                                   short* __restrict__ outq,
                                                   short* __restrict__ outk,
                                                   short* __restrict__ outv,
                                                   float* __restrict__ outf) {
  __shared__ short As[128*32];
  __shared__ short Bs[128*32];
  const int bx = blockIdx.x, by = blockIdx.y, z = blockIdx.z;
  const short* Bz = Bw + (size_t)z * DIM * DIM;
  const int tid = threadIdx.x, w = tid>>6, lane = tid&63;
  const int wr = w>>1, wc = w&1, ln15 = lane&15, lg = lane>>4;
  const int m0 = by*128, n0 = bx*128;

  f32x4 acc[4][4] = {};

  for (int kt=0; kt<24; ++kt) {
    const int k0 = kt*32;
    __syncthreads();
#pragma unroll
    for (int i=0;i<2;i++) {
      const int inst = w*2 + i;
      const int off  = inst*1024 + lane*16;
      const int row  = off >> 6;
      const int ce   = (off & 63) >> 1;
      gld_lds16(A  + (size_t)(m0+row)*DIM + k0 + ce, (char*)As + (size_t)inst*1024);
      gld_lds16(Bz + (size_t)(n0+row)*DIM + k0 + ce, (char*)Bs + (size_t)inst*1024);
    }
    __syncthreads();
    bf16x8 af[4], bfr_[4];
#pragma unroll
    for (int mi=0;mi<4;mi++) af[mi]   = *(const bf16x8*)&As[(wr*64+mi*16+ln15)*32 + lg*8];
#pragma unroll
    for (int ni=0;ni<4;ni++) bfr_[ni] = *(const bf16x8*)&Bs[(wc*64+ni*16+ln15)*32 + lg*8];
#pragma unroll
    for (int mi=0;mi<4;mi++)
#pragma unroll
      for (int ni=0;ni<4;ni++)
        acc[mi][ni] = __builtin_amdgcn_mfma_f32_16x16x32_bf16(af[mi], bfr_[ni], acc[mi][ni], 0,0,0);
  }

  if (MODE == 0) {
    const float scl = (z==0) ? 0.125f * L2E : 1.0f;   // Q pre-scaled into log2 domain
#pragma unroll
    for (int mi=0;mi<4;mi++) {
#pragma unroll
      for (int j=0;j<4;j++) {
        const int r  = m0 + wr*64 + mi*16 + lg*4 + j;
        const int bb = r / NP;
        const int m  = r - bb*NP;
        const float* tv = aux + ((size_t)z*BATCH + bb) * DIM;
        if (z == 0) {
#pragma unroll
          for (int ni=0;ni<4;ni++) {
            const int gcol = n0 + wc*64 + ni*16 + ln15;
            outq[(size_t)r*DIM + gcol] = f2bf((acc[mi][ni][j] + tv[gcol]) * scl);
          }
        } else if (z == 1) {
#pragma unroll
          for (int ni=0;ni<4;ni++) {
            const int gcol = n0 + wc*64 + ni*16 + ln15;
            const int h = gcol >> 6, d = gcol & 63;
            outk[((size_t)(bb*NH + h)*MPAD + m)*HD + d] = f2bf(acc[mi][ni][j] + tv[gcol]);
          }
        }
      }
      if (MODE == 0 && z == 2) {
        const int r0 = m0 + wr*64 + mi*16 + lg*4;
        const int bb = r0 / NP;
        const int m  = r0 - bb*NP;          // group of 4 never crosses batch (784%4==0)
        const float* tv = aux + ((size_t)2*BATCH + bb) * DIM;
#pragma unroll
        for (int ni=0;ni<4;ni++) {
          const int gcol = n0 + wc*64 + ni*16 + ln15;
          const int h = gcol >> 6, d = gcol & 63;
          const float tb = tv[gcol];
          bf16x4 ov;
          ov[0] = f2bf(acc[mi][ni][0] + tb);
          ov[1] = f2bf(acc[mi][ni][1] + tb);
          ov[2] = f2bf(acc[mi][ni][2] + tb);
          ov[3] = f2bf(acc[mi][ni][3] + tb);
          *(bf16x4*)&outv[((size_t)(bb*NH + h)*HD + d)*MPAD + m] = ov;
        }
      }
    }
  } else {
#pragma unroll
    for (int mi=0;mi<4;mi++)
#pragma unroll
      for (int j=0;j<4;j++) {
        const int r = m0 + wr*64 + mi*16 + lg*4 + j;
#pragma unroll
        for (int ni=0;ni<4;ni++) {
          const int gcol = n0 + wc*64 + ni*16 + ln15;
          outf[(size_t)r*DIM + gcol] = acc[mi][ni][j] + aux[gcol];
        }
      }
  }
}

// ---------------- flash attention v3 ----------------
// 1248 blocks flattened; XCD-gather swizzle: logical=(hw&7)*156+(hw>>3) puts all 13 q-tiles
// of each (b,h) — and 12 whole (b,h) groups — on ONE XCD (1248 = 8*156, 156 = 12*13).
// log2-domain softmax (scale folded into Q, bias table x log2e), defer-max THR=8.
__global__ __launch_bounds__(256) void attn3_kernel(const short* __restrict__ Qb,
                                                    const short* __restrict__ Kt,
                                                    const short* __restrict__ Vt,
                                                    const float* __restrict__ rpb,
                                                    short* __restrict__ Ob) {
  __shared__ short kt[2][4096];    // K tile [64 m][64 d], byte ^= (row&7)<<4 swizzle
  __shared__ short vt[2][4096];    // V^T tile [64 d][64 m], same swizzle
  __shared__ float bias_ext[112];
  const int hw = blockIdx.x;
  const int lgid = (hw & 7) * 156 + (hw >> 3);
  const int qt = lgid % 13;
  const int bh = lgid / 13;
  const int h = bh % NH, b = bh / NH;
  const int q0 = qt*64, tid = threadIdx.x, w = tid >> 6, lane = tid & 63;
  const int ln15 = lane & 15, lg = lane >> 4;

  if (tid < 109) bias_ext[tid + 2] = rpb[(tid/55)*(55*NH) + (tid%55)*NH + h] * L2E;
  if (tid == 109) { bias_ext[0] = 0.f; bias_ext[1] = 0.f; bias_ext[111] = 0.f; }

  const bool active = (q0 + w*16) < NP;
  const int q_idx = q0 + w*16 + ln15;
  bf16x8 qf0 = {}, qf1 = {};
  if (active) {
    const short* qp = Qb + ((size_t)(b*NP) + q_idx)*DIM + h*HD + lg*8;
    qf0 = *(const bf16x8*)qp;
    qf1 = *(const bf16x8*)(qp + 32);
  }
  const int qs56 = q_idx/28 + q_idx%28 + 56;

  const int lr = lane >> 3, lc = lane & 7;
  const int swe = (lc ^ lr) << 3;
  const size_t bhs = (size_t)bh;
  const short* kp0 = Kt + (bhs*MPAD + (size_t)(w*8 + lr))*HD + swe;
  const short* kp1 = kp0 + 32*HD;
  const short* vp0 = Vt + (bhs*HD + (size_t)(w*8 + lr))*MPAD + swe;
  const short* vp1 = vp0 + 32*MPAD;

#define STAGE4(BUF) { \
    char* kb_ = (char*)kt[BUF]; char* vb_ = (char*)vt[BUF]; \
    gld_lds16(kp0, kb_ + w*1024); \
    gld_lds16(kp1, kb_ + (w+4)*1024); \
    gld_lds16(vp0, vb_ + w*1024); \
    gld_lds16(vp1, vb_ + (w+4)*1024); \
    kp0 += 64*HD; kp1 += 64*HD; vp0 += 64; vp1 += 64; }

  float m_run = -3.0e38f, l_run = 0.f;
  f32x4 o0 = {}, o1 = {}, o2 = {}, o3 = {};

  STAGE4(0)

  for (int t = 0; t < 13; ++t) {
    const int cur = t & 1;
    const int m0 = t * 64;
    __syncthreads();
    if (t < 12) STAGE4(cur^1)
    if (active) {
      const char* kb = (const char*)kt[cur];
      const int sw = (ln15 & 7) << 4;
      f32x4 s[4];
#pragma unroll
      for (int mc = 0; mc < 4; ++mc) {
        const int rb = (mc*16 + ln15) * 128;
        bf16x8 kf0 = *(const bf16x8*)(kb + rb + ((lg*16) ^ sw));
        bf16x8 kf1 = *(const bf16x8*)(kb + rb + ((lg*16 + 64) ^ sw));
        f32x4 acc = {};
        acc = __builtin_amdgcn_mfma_f32_16x16x32_bf16(kf0, qf0, acc, 0,0,0);
        acc = __builtin_amdgcn_mfma_f32_16x16x32_bf16(kf1, qf1, acc, 0,0,0);
        s[mc] = acc;
      }
      // bias: within a j-quad ms is consecutive (mb%4==0, 28%4==0 -> no /28 crossing)
#pragma unroll
      for (int mc = 0; mc < 4; ++mc) {
        const int mb = m0 + mc*16 + lg*4;
        const int a28 = (mb * 2341) >> 16;          // mb/28 (exact for mb<5400)
        const int idx0 = qs56 - mb + 27*a28;        // qs+56 - ms(mb)
        s[mc][0] += bias_ext[idx0];
        s[mc][1] += bias_ext[idx0-1];
        s[mc][2] += bias_ext[idx0-2];
        s[mc][3] += bias_ext[idx0-3];
      }
      if (m0 + 64 > NP) {
#pragma unroll
        for (int mc = 0; mc < 4; ++mc)
#pragma unroll
          for (int j = 0; j < 4; ++j)
            if (m0 + mc*16 + lg*4 + j >= NP) s[mc][j] = -1e30f;
      }
      // tile max (max3-friendly trees) + lg-group reduce
      float t0 = fmaxf(fmaxf(s[0][0],s[0][1]), fmaxf(s[0][2],s[0][3]));
      float t1 = fmaxf(fmaxf(s[1][0],s[1][1]), fmaxf(s[1][2],s[1][3]));
      float t2 = fmaxf(fmaxf(s[2][0],s[2][1]), fmaxf(s[2][2],s[2][3]));
      float t3 = fmaxf(fmaxf(s[3][0],s[3][1]), fmaxf(s[3][2],s[3][3]));
      float tm = fmaxf(fmaxf(t0,t1), fmaxf(t2,t3));
      tm = fmaxf(tm, __shfl_xor(tm, 16));
      tm = fmaxf(tm, __shfl_xor(tm, 32));
      // defer-max: skip rescale when tile max doesn't grow past m_run+8 (P bounded by 2^8)
      const bool grow = !__all(tm - m_run <= 8.0f);
      float m_new = m_run, f = 1.0f;
      if (grow) { m_new = fmaxf(m_run, tm); f = exp2f(m_run - m_new); }
      float ts = 0.f;
#pragma unroll
      for (int mc = 0; mc < 4; ++mc) {
        float p0 = exp2f(s[mc][0]-m_new), p1 = exp2f(s[mc][1]-m_new);
        float p2 = exp2f(s[mc][2]-m_new), p3 = exp2f(s[mc][3]-m_new);
        s[mc][0]=p0; s[mc][1]=p1; s[mc][2]=p2; s[mc][3]=p3;
        ts += (p0+p1)+(p2+p3);
      }
      ts += __shfl_xor(ts, 16);
      ts += __shfl_xor(ts, 32);
      if (grow) {
        l_run = l_run * f + ts;
        m_run = m_new;
        o0 *= f; o1 *= f; o2 *= f; o3 *= f;
      } else {
        l_run += ts;
      }
      bf16x4 pb[4];
#pragma unroll
      for (int mc = 0; mc < 4; ++mc) {
        pb[mc][0] = bfr(s[mc][0]); pb[mc][1] = bfr(s[mc][1]);
        pb[mc][2] = bfr(s[mc][2]); pb[mc][3] = bfr(s[mc][3]);
      }
      const char* vb = (const char*)vt[cur];
#pragma unroll
      for (int mc = 0; mc < 4; ++mc) {
        const int ib = (mc*32 + lg*8) ^ sw;
        bf16x4 vf0 = *(const bf16x4*)(vb + (0*16+ln15)*128 + ib);
        bf16x4 vf1 = *(const bf16x4*)(vb + (1*16+ln15)*128 + ib);
        bf16x4 vf2 = *(const bf16x4*)(vb + (2*16+ln15)*128 + ib);
        bf16x4 vf3 = *(const bf16x4*)(vb + (3*16+ln15)*128 + ib);
        o0 = __builtin_amdgcn_mfma_f32_16x16x16bf16_1k(vf0, pb[mc], o0, 0,0,0);
        o1 = __builtin_amdgcn_mfma_f32_16x16x16bf16_1k(vf1, pb[mc], o1, 0,0,0);
        o2 = __builtin_amdgcn_mfma_f32_16x16x16bf16_1k(vf2, pb[mc], o2, 0,0,0);
        o3 = __builtin_amdgcn_mfma_f32_16x16x16bf16_1k(vf3, pb[mc], o3, 0,0,0);
      }
    }
  }
#undef STAGE4

  if (active) {
    const float inv = 1.0f / l_run;
    short* op = Ob + ((size_t)(b*NP) + q_idx)*DIM + h*HD + lg*4;
    bf16x4 ov;
    ov[0]=bfr(o0[0]*inv); ov[1]=bfr(o0[1]*inv); ov[2]=bfr(o0[2]*inv); ov[3]=bfr(o0[3]*inv);
    *(bf16x4*)(op + 0*16) = ov;
    ov[0]=bfr(o1[0]*inv); ov[1]=bfr(o1[1]*inv); ov[2]=bfr(o1[2]*inv); ov[3]=bfr(o1[3]*inv);
    *(bf16x4*)(op + 1*16) = ov;
    ov[0]=bfr(o2[0]*inv); ov[1]=bfr(o2[1]*inv); ov[2]=bfr(o2[2]*inv); ov[3]=bfr(o2[3]*inv);
    *(bf16x4*)(op + 2*16) = ov;
    ov[0]=bfr(o3[0]*inv); ov[1]=bfr(o3[1]*inv); ov[2]=bfr(o3[2]*inv); ov[3]=bfr(o3[3]*inv);
    *(bf16x4*)(op + 3*16) = ov;
  }
}

extern "C" void kernel_launch(void* const* d_in, const int* in_sizes, int n_in,
                              void* d_out, int out_size, void* d_ws, size_t ws_size,
                              hipStream_t stream) {
  const float* x_s = (const float*)d_in[0];
  const float* x_t = (const float*)d_in[1];
  const float* Wqs = (const float*)d_in[2];
  const float* Wqt = (const float*)d_in[3];
  const float* Wks = (const float*)d_in[4];
  const float* Wkt = (const float*)d_in[5];
  const float* Wvs = (const float*)d_in[6];
  const float* Wvt = (const float*)d_in[7];
  const float* rpb = (const float*)d_in[8];
  const float* pw  = (const float*)d_in[9];
  const float* pb  = (const float*)d_in[10];
  float* out = (float*)d_out;

  char* ws = (char*)d_ws;
  size_t off = 0;
  float* t_part = (float*)(ws + off); off += (size_t)3*NCHUNK*BATCH*DIM*4;
  float* t_vec  = (float*)(ws + off); off += (size_t)3*BATCH*DIM*4;
  short* Wt     = (short*)(ws + off); off += (size_t)4*DIM*DIM*2;
  short* Qb     = (short*)(ws + off); off += (size_t)MROWS*DIM*2;
  short* Ob     = (short*)(ws + off); off += (size_t)MROWS*DIM*2;
  short* Xb     = (short*)(ws + off); off += (size_t)MROWS*DIM*2;
  short* Kt     = (short*)(ws + off); off += (size_t)BATCH*NH*MPAD*HD*2;
  short* Vt     = (short*)(ws + off); off += (size_t)BATCH*NH*MPAD*HD*2;
  // total ~57 MB

  cvt_bf16_kernel<<<2352, 256, 0, stream>>>(x_s, Xb, MROWS*DIM/8);
  wtrans_kernel<<<dim3(24,24,4), dim3(32,8), 0, stream>>>(Wqs, Wks, Wvs, pw, Wt);
  tvec1_kernel<<<dim3(3,NCHUNK), 256, 0, stream>>>(x_t, Wqt, Wkt, Wvt, t_part);
  tvec2_kernel<<<72, 256, 0, stream>>>(t_part, t_vec);
  gemm_kernel<0><<<dim3(6,49,3), 256, 0, stream>>>(Xb, Wt, t_vec, Qb, Kt, Vt, nullptr);
  attn3_kernel<<<1248, 256, 0, stream>>>(Qb, Kt, Vt, rpb, Ob);
  gemm_kernel<1><<<dim3(6,49,1), 256, 0, stream>>>(Ob, Wt + (size_t)3*DIM*DIM, pb,
                                                   nullptr, nullptr, nullptr, out);
}

// Round 5
// 134.193 us; speedup vs baseline: 1.8853x; 1.0390x over previous
//
#include <hip/hip_runtime.h>
#include <hip/hip_bf16.h>
#include <stdint.h>

#define DIM 768
#define NP  784
#define NH  12
#define HD  64
#define BATCH 8
#define MROWS (BATCH*NP)   // 6272
#define MPAD 832           // 13*64
#define NCHUNK 32
#define KCH 24             // 768/32
#define L2E 1.4426950408889634f

using bf16x8 = __attribute__((ext_vector_type(8))) short;
using bf16x4 = __attribute__((ext_vector_type(4))) short;
using f32x4  = __attribute__((ext_vector_type(4))) float;

__device__ __forceinline__ short f2bf(float f) {
  union { float f; uint32_t u; } c; c.f = f;
  uint32_t u = c.u;
  u += 0x7FFFu + ((u >> 16) & 1u);   // RNE
  return (short)(u >> 16);
}

// native path: compiler emits v_cvt_pk_bf16_f32 for adjacent pairs (m240)
__device__ __forceinline__ short bfr(float x) {
  union { __hip_bfloat16 b; short s; } u;
  u.b = __float2bfloat16(x);
  return u.s;
}

__device__ __forceinline__ void gld_lds16(const void* g, void* l) {
  __builtin_amdgcn_global_load_lds((const __attribute__((address_space(1))) uint32_t*)g,
                                   (__attribute__((address_space(3))) uint32_t*)l,
                                   16, 0, 0);
}

// ---------------- prep: x_s -> bf16 ----------------
__global__ __launch_bounds__(256) void cvt_bf16_kernel(const float* __restrict__ src,
                                                       short* __restrict__ dst, int n8) {
  int i = blockIdx.x * 256 + threadIdx.x;
  if (i >= n8) return;
  const float4* s = (const float4*)src;
  float4 a = s[2*i], b = s[2*i+1];
  bf16x8 o;
  o[0]=f2bf(a.x); o[1]=f2bf(a.y); o[2]=f2bf(a.z); o[3]=f2bf(a.w);
  o[4]=f2bf(b.x); o[5]=f2bf(b.y); o[6]=f2bf(b.z); o[7]=f2bf(b.w);
  ((bf16x8*)dst)[i] = o;
}

// ---------------- prep: W[k][n] -> Wt[n][k] bf16 (4 matrices) ----------------
__global__ __launch_bounds__(256) void wtrans_kernel(const float* __restrict__ w0,
                                                     const float* __restrict__ w1,
                                                     const float* __restrict__ w2,
                                                     const float* __restrict__ w3,
                                                     short* __restrict__ dst) {
  __shared__ float tile[32][33];
  const int z = blockIdx.z;
  const float* src = (z==0) ? w0 : (z==1) ? w1 : (z==2) ? w2 : w3;
  short* d = dst + (size_t)z * DIM * DIM;
  const int n0 = blockIdx.x*32, k0 = blockIdx.y*32;
  const int tx = threadIdx.x, ty = threadIdx.y;  // (32,8)
#pragma unroll
  for (int i=0;i<4;i++) tile[ty+i*8][tx] = src[(size_t)(k0+ty+i*8)*DIM + n0+tx];
  __syncthreads();
#pragma unroll
  for (int i=0;i<4;i++) d[(size_t)(n0+ty+i*8)*DIM + k0+tx] = f2bf(tile[tx][ty+i*8]);
}

// ---------------- prep: split-k GEMV partials: part[z][kc][b][d] ----------------
__global__ __launch_bounds__(256) void tvec1_kernel(const float* __restrict__ x_t,
                                                    const float* __restrict__ wq,
                                                    const float* __restrict__ wk,
                                                    const float* __restrict__ wv,
                                                    float* __restrict__ part) {
  const int z = blockIdx.x, kc = blockIdx.y;
  const float* w = (z==0) ? wq : (z==1) ? wk : wv;
  const int d = threadIdx.x;
  __shared__ float xs[BATCH][KCH];
  if (threadIdx.x < BATCH*KCH)
    xs[threadIdx.x / KCH][threadIdx.x % KCH] =
        x_t[(size_t)(threadIdx.x / KCH)*DIM + kc*KCH + threadIdx.x % KCH];
  __syncthreads();
  float a0[BATCH] = {}, a1[BATCH] = {}, a2[BATCH] = {};
#pragma unroll 4
  for (int k = 0; k < KCH; ++k) {
    const float* wr = w + (size_t)(kc*KCH + k)*DIM + d;
    float w0 = wr[0], w1 = wr[256], w2 = wr[512];
#pragma unroll
    for (int b = 0; b < BATCH; ++b) {
      float xv = xs[b][k];
      a0[b] += xv*w0; a1[b] += xv*w1; a2[b] += xv*w2;
    }
  }
#pragma unroll
  for (int b = 0; b < BATCH; ++b) {
    float* p = part + (((size_t)z*NCHUNK + kc)*BATCH + b)*DIM + d;
    p[0] = a0[b]; p[256] = a1[b]; p[512] = a2[b];
  }
}

// ---------------- reduce partials -> t[z][b][d] ----------------
__global__ __launch_bounds__(256) void tvec2_kernel(const float* __restrict__ part,
                                                    float* __restrict__ t) {
  const int i = blockIdx.x*256 + threadIdx.x;   // 3*8*768 = 18432
  if (i >= 3*BATCH*DIM) return;
  const int z = i / (BATCH*DIM), rem = i % (BATCH*DIM);
  float s = 0.f;
#pragma unroll 8
  for (int c = 0; c < NCHUNK; ++c)
    s += part[((size_t)z*NCHUNK + c)*BATCH*DIM + rem];
  t[i] = s;
}

// ---------------- GEMM: C[m][n] = A[m][k] * Bt[n][k]  (bf16 in, f32 acc) ----------------
// MODE 0: QKV — adds t-vec; z=0 -> Q (x 0.125*log2e, std layout), z=1 -> Kt, z=2 -> Vt transposed
// MODE 1: proj — adds bias, stores f32
template<int MODE>
__global__ __launch_bounds__(256) void gemm_kernel(const short* __restrict__ A,
                                                   const short* __restrict__ Bw,
                                                   const float* __restrict__ aux,
                                                   short* __restrict__ outq,
                                                   short* __restrict__ outk,
                                                   short* __restrict__ outv,
                                                   float* __restrict__ outf) {
  __shared__ short As[128*32];
  __shared__ short Bs[128*32];
  const int bx = blockIdx.x, by = blockIdx.y, z = blockIdx.z;
  const short* Bz = Bw + (size_t)z * DIM * DIM;
  const int tid = threadIdx.x, w = tid>>6, lane = tid&63;
  const int wr = w>>1, wc = w&1, ln15 = lane&15, lg = lane>>4;
  const int m0 = by*128, n0 = bx*128;

  f32x4 acc[4][4] = {};

  for (int kt=0; kt<24; ++kt) {
    const int k0 = kt*32;
    __syncthreads();
#pragma unroll
    for (int i=0;i<2;i++) {
      const int inst = w*2 + i;
      const int off  = inst*1024 + lane*16;
      const int row  = off >> 6;
      const int ce   = (off & 63) >> 1;
      gld_lds16(A  + (size_t)(m0+row)*DIM + k0 + ce, (char*)As + (size_t)inst*1024);
      gld_lds16(Bz + (size_t)(n0+row)*DIM + k0 + ce, (char*)Bs + (size_t)inst*1024);
    }
    __syncthreads();
    bf16x8 af[4], bfr_[4];
#pragma unroll
    for (int mi=0;mi<4;mi++) af[mi]   = *(const bf16x8*)&As[(wr*64+mi*16+ln15)*32 + lg*8];
#pragma unroll
    for (int ni=0;ni<4;ni++) bfr_[ni] = *(const bf16x8*)&Bs[(wc*64+ni*16+ln15)*32 + lg*8];
#pragma unroll
    for (int mi=0;mi<4;mi++)
#pragma unroll
      for (int ni=0;ni<4;ni++)
        acc[mi][ni] = __builtin_amdgcn_mfma_f32_16x16x32_bf16(af[mi], bfr_[ni], acc[mi][ni], 0,0,0);
  }

  if (MODE == 0) {
    const float scl = (z==0) ? 0.125f * L2E : 1.0f;   // Q pre-scaled into log2 domain
#pragma unroll
    for (int mi=0;mi<4;mi++) {
#pragma unroll
      for (int j=0;j<4;j++) {
        const int r  = m0 + wr*64 + mi*16 + lg*4 + j;
        const int bb = r / NP;
        const int m  = r - bb*NP;
        const float* tv = aux + ((size_t)z*BATCH + bb) * DIM;
        if (z == 0) {
#pragma unroll
          for (int ni=0;ni<4;ni++) {
            const int gcol = n0 + wc*64 + ni*16 + ln15;
            outq[(size_t)r*DIM + gcol] = f2bf((acc[mi][ni][j] + tv[gcol]) * scl);
          }
        } else if (z == 1) {
#pragma unroll
          for (int ni=0;ni<4;ni++) {
            const int gcol = n0 + wc*64 + ni*16 + ln15;
            const int h = gcol >> 6, d = gcol & 63;
            outk[((size_t)(bb*NH + h)*MPAD + m)*HD + d] = f2bf(acc[mi][ni][j] + tv[gcol]);
          }
        }
      }
      if (MODE == 0 && z == 2) {
        const int r0 = m0 + wr*64 + mi*16 + lg*4;
        const int bb = r0 / NP;
        const int m  = r0 - bb*NP;          // group of 4 never crosses batch (784%4==0)
        const float* tv = aux + ((size_t)2*BATCH + bb) * DIM;
#pragma unroll
        for (int ni=0;ni<4;ni++) {
          const int gcol = n0 + wc*64 + ni*16 + ln15;
          const int h = gcol >> 6, d = gcol & 63;
          const float tb = tv[gcol];
          bf16x4 ov;
          ov[0] = f2bf(acc[mi][ni][0] + tb);
          ov[1] = f2bf(acc[mi][ni][1] + tb);
          ov[2] = f2bf(acc[mi][ni][2] + tb);
          ov[3] = f2bf(acc[mi][ni][3] + tb);
          *(bf16x4*)&outv[((size_t)(bb*NH + h)*HD + d)*MPAD + m] = ov;
        }
      }
    }
  } else {
#pragma unroll
    for (int mi=0;mi<4;mi++)
#pragma unroll
      for (int j=0;j<4;j++) {
        const int r = m0 + wr*64 + mi*16 + lg*4 + j;
#pragma unroll
        for (int ni=0;ni<4;ni++) {
          const int gcol = n0 + wc*64 + ni*16 + ln15;
          outf[(size_t)r*DIM + gcol] = acc[mi][ni][j] + aux[gcol];
        }
      }
  }
}

// ---------------- flash attention v4: 8-wave blocks (QBLK=128), shared K/V staging ----------------
// 672 blocks = 96 bh-groups x 7 q-tiles = 8 XCDs x 84; XCD-gather: logical=(hw&7)*84+(hw>>3)
// puts 12 whole (b,h) groups on each XCD. Per-wave code identical to v3 (16 q-rows/wave);
// the 8 waves share one K/V double-buffer -> 2x waves/CU at the same LDS footprint.
__global__ __launch_bounds__(512) void attn4_kernel(const short* __restrict__ Qb,
                                                    const short* __restrict__ Kt,
                                                    const short* __restrict__ Vt,
                                                    const float* __restrict__ rpb,
                                                    short* __restrict__ Ob) {
  __shared__ short kt[2][4096];    // K tile [64 m][64 d], byte ^= (row&7)<<4 swizzle
  __shared__ short vt[2][4096];    // V^T tile [64 d][64 m], same swizzle
  __shared__ float4 bias4[112];    // bias4[i] = {be[i], be[i-1], be[i-2], be[i-3]}, be in log2 dom.
  const int hw = blockIdx.x;
  const int lgid = (hw & 7) * 84 + (hw >> 3);
  const int qt = lgid % 7;
  const int bh = lgid / 7;
  const int h = bh % NH, b = bh / NH;
  const int q0 = qt*128, tid = threadIdx.x, w = tid >> 6, lane = tid & 63;
  const int ln15 = lane & 15, lg = lane >> 4;

  if (tid < 112) {
    float4 v;
#pragma unroll
    for (int j = 0; j < 4; ++j) {
      const int i = tid - j - 2;   // bias_ext index minus offset
      float bv = 0.f;
      if (i >= 0 && i < 109)
        bv = rpb[(i/55)*(55*NH) + (i%55)*NH + h] * L2E;
      ((float*)&v)[j] = bv;
    }
    bias4[tid] = v;
  }

  const bool active = (q0 + w*16) < NP;
  const int q_idx = q0 + w*16 + ln15;
  bf16x8 qf0 = {}, qf1 = {};
  if (active) {
    const short* qp = Qb + ((size_t)(b*NP) + q_idx)*DIM + h*HD + lg*8;
    qf0 = *(const bf16x8*)qp;
    qf1 = *(const bf16x8*)(qp + 32);
  }
  const int qs56 = q_idx/28 + q_idx%28 + 56;

  // wave w stages rows [w*8, w*8+8) of both tiles (1 KB each)
  const int lr = lane >> 3, lc = lane & 7;
  const int swe = (lc ^ lr) << 3;
  const size_t bhs = (size_t)bh;
  const short* kp0 = Kt + (bhs*MPAD + (size_t)(w*8 + lr))*HD + swe;
  const short* vp0 = Vt + (bhs*HD + (size_t)(w*8 + lr))*MPAD + swe;

#define STAGE2(BUF) { \
    gld_lds16(kp0, (char*)kt[BUF] + w*1024); \
    gld_lds16(vp0, (char*)vt[BUF] + w*1024); \
    kp0 += 64*HD; vp0 += 64; }

  float m_run = -3.0e38f, l_run = 0.f;
  f32x4 o0 = {}, o1 = {}, o2 = {}, o3 = {};

  STAGE2(0)

  for (int t = 0; t < 13; ++t) {
    const int cur = t & 1;
    const int m0 = t * 64;
    __syncthreads();
    if (t < 12) STAGE2(cur^1)
    if (active) {
      const char* kb = (const char*)kt[cur];
      const int sw = (ln15 & 7) << 4;
      f32x4 s[4];
#pragma unroll
      for (int mc = 0; mc < 4; ++mc) {
        const int rb = (mc*16 + ln15) * 128;
        bf16x8 kf0 = *(const bf16x8*)(kb + rb + ((lg*16) ^ sw));
        bf16x8 kf1 = *(const bf16x8*)(kb + rb + ((lg*16 + 64) ^ sw));
        f32x4 acc = {};
        acc = __builtin_amdgcn_mfma_f32_16x16x32_bf16(kf0, qf0, acc, 0,0,0);
        acc = __builtin_amdgcn_mfma_f32_16x16x32_bf16(kf1, qf1, acc, 0,0,0);
        s[mc] = acc;
      }
      // bias: one float4 LDS read per mc (j-quad is consecutive, reversed, in the table)
#pragma unroll
      for (int mc = 0; mc < 4; ++mc) {
        const int mb = m0 + mc*16 + lg*4;
        const int a28 = (mb * 2341) >> 16;          // mb/28 (exact for mb<5400)
        const int idx0 = qs56 - mb + 27*a28;        // in [2,110]
        const float4 b4 = bias4[idx0];
        s[mc][0] += b4.x;
        s[mc][1] += b4.y;
        s[mc][2] += b4.z;
        s[mc][3] += b4.w;
      }
      if (m0 + 64 > NP) {
#pragma unroll
        for (int mc = 0; mc < 4; ++mc)
#pragma unroll
          for (int j = 0; j < 4; ++j)
            if (m0 + mc*16 + lg*4 + j >= NP) s[mc][j] = -1e30f;
      }
      // tile max + lg-group reduce
      float t0 = fmaxf(fmaxf(s[0][0],s[0][1]), fmaxf(s[0][2],s[0][3]));
      float t1 = fmaxf(fmaxf(s[1][0],s[1][1]), fmaxf(s[1][2],s[1][3]));
      float t2 = fmaxf(fmaxf(s[2][0],s[2][1]), fmaxf(s[2][2],s[2][3]));
      float t3 = fmaxf(fmaxf(s[3][0],s[3][1]), fmaxf(s[3][2],s[3][3]));
      float tm = fmaxf(fmaxf(t0,t1), fmaxf(t2,t3));
      tm = fmaxf(tm, __shfl_xor(tm, 16));
      tm = fmaxf(tm, __shfl_xor(tm, 32));
      // defer-max: skip rescale while tile max stays within m_run+8 (P bounded by 2^8)
      const bool grow = !__all(tm - m_run <= 8.0f);
      float m_new = m_run, f = 1.0f;
      if (grow) { m_new = fmaxf(m_run, tm); f = exp2f(m_run - m_new); }
      float ts = 0.f;
#pragma unroll
      for (int mc = 0; mc < 4; ++mc) {
        float p0 = exp2f(s[mc][0]-m_new), p1 = exp2f(s[mc][1]-m_new);
        float p2 = exp2f(s[mc][2]-m_new), p3 = exp2f(s[mc][3]-m_new);
        s[mc][0]=p0; s[mc][1]=p1; s[mc][2]=p2; s[mc][3]=p3;
        ts += (p0+p1)+(p2+p3);
      }
      ts += __shfl_xor(ts, 16);
      ts += __shfl_xor(ts, 32);
      if (grow) {
        l_run = l_run * f + ts;
        m_run = m_new;
        o0 *= f; o1 *= f; o2 *= f; o3 *= f;
      } else {
        l_run += ts;
      }
      bf16x4 pb[4];
#pragma unroll
      for (int mc = 0; mc < 4; ++mc) {
        pb[mc][0] = bfr(s[mc][0]); pb[mc][1] = bfr(s[mc][1]);
        pb[mc][2] = bfr(s[mc][2]); pb[mc][3] = bfr(s[mc][3]);
      }
      const char* vb = (const char*)vt[cur];
#pragma unroll
      for (int mc = 0; mc < 4; ++mc) {
        const int ib = (mc*32 + lg*8) ^ sw;
        bf16x4 vf0 = *(const bf16x4*)(vb + (0*16+ln15)*128 + ib);
        bf16x4 vf1 = *(const bf16x4*)(vb + (1*16+ln15)*128 + ib);
        bf16x4 vf2 = *(const bf16x4*)(vb + (2*16+ln15)*128 + ib);
        bf16x4 vf3 = *(const bf16x4*)(vb + (3*16+ln15)*128 + ib);
        o0 = __builtin_amdgcn_mfma_f32_16x16x16bf16_1k(vf0, pb[mc], o0, 0,0,0);
        o1 = __builtin_amdgcn_mfma_f32_16x16x16bf16_1k(vf1, pb[mc], o1, 0,0,0);
        o2 = __builtin_amdgcn_mfma_f32_16x16x16bf16_1k(vf2, pb[mc], o2, 0,0,0);
        o3 = __builtin_amdgcn_mfma_f32_16x16x16bf16_1k(vf3, pb[mc], o3, 0,0,0);
      }
    }
  }
#undef STAGE2

  if (active) {
    const float inv = 1.0f / l_run;
    short* op = Ob + ((size_t)(b*NP) + q_idx)*DIM + h*HD + lg*4;
    bf16x4 ov;
    ov[0]=bfr(o0[0]*inv); ov[1]=bfr(o0[1]*inv); ov[2]=bfr(o0[2]*inv); ov[3]=bfr(o0[3]*inv);
    *(bf16x4*)(op + 0*16) = ov;
    ov[0]=bfr(o1[0]*inv); ov[1]=bfr(o1[1]*inv); ov[2]=bfr(o1[2]*inv); ov[3]=bfr(o1[3]*inv);
    *(bf16x4*)(op + 1*16) = ov;
    ov[0]=bfr(o2[0]*inv); ov[1]=bfr(o2[1]*inv); ov[2]=bfr(o2[2]*inv); ov[3]=bfr(o2[3]*inv);
    *(bf16x4*)(op + 2*16) = ov;
    ov[0]=bfr(o3[0]*inv); ov[1]=bfr(o3[1]*inv); ov[2]=bfr(o3[2]*inv); ov[3]=bfr(o3[3]*inv);
    *(bf16x4*)(op + 3*16) = ov;
  }
}

extern "C" void kernel_launch(void* const* d_in, const int* in_sizes, int n_in,
                              void* d_out, int out_size, void* d_ws, size_t ws_size,
                              hipStream_t stream) {
  const float* x_s = (const float*)d_in[0];
  const float* x_t = (const float*)d_in[1];
  const float* Wqs = (const float*)d_in[2];
  const float* Wqt = (const float*)d_in[3];
  const float* Wks = (const float*)d_in[4];
  const float* Wkt = (const float*)d_in[5];
  const float* Wvs = (const float*)d_in[6];
  const float* Wvt = (const float*)d_in[7];
  const float* rpb = (const float*)d_in[8];
  const float* pw  = (const float*)d_in[9];
  const float* pb  = (const float*)d_in[10];
  float* out = (float*)d_out;

  char* ws = (char*)d_ws;
  size_t off = 0;
  float* t_part = (float*)(ws + off); off += (size_t)3*NCHUNK*BATCH*DIM*4;
  float* t_vec  = (float*)(ws + off); off += (size_t)3*BATCH*DIM*4;
  short* Wt     = (short*)(ws + off); off += (size_t)4*DIM*DIM*2;
  short* Qb     = (short*)(ws + off); off += (size_t)MROWS*DIM*2;
  short* Ob     = (short*)(ws + off); off += (size_t)MROWS*DIM*2;
  short* Xb     = (short*)(ws + off); off += (size_t)MROWS*DIM*2;
  short* Kt     = (short*)(ws + off); off += (size_t)BATCH*NH*MPAD*HD*2;
  short* Vt     = (short*)(ws + off); off += (size_t)BATCH*NH*MPAD*HD*2;
  // total ~57 MB

  cvt_bf16_kernel<<<2352, 256, 0, stream>>>(x_s, Xb, MROWS*DIM/8);
  wtrans_kernel<<<dim3(24,24,4), dim3(32,8), 0, stream>>>(Wqs, Wks, Wvs, pw, Wt);
  tvec1_kernel<<<dim3(3,NCHUNK), 256, 0, stream>>>(x_t, Wqt, Wkt, Wvt, t_part);
  tvec2_kernel<<<72, 256, 0, stream>>>(t_part, t_vec);
  gemm_kernel<0><<<dim3(6,49,3), 256, 0, stream>>>(Xb, Wt, t_vec, Qb, Kt, Vt, nullptr);
  attn4_kernel<<<672, 512, 0, stream>>>(Qb, Kt, Vt, rpb, Ob);
  gemm_kernel<1><<<dim3(6,49,1), 256, 0, stream>>>(Ob, Wt + (size_t)3*DIM*DIM, pb,
                                                   nullptr, nullptr, nullptr, out);
}